// Round 5
// baseline (242.684 us; speedup 1.0000x reference)
//
#include <hip/hip_runtime.h>
#include <hip/hip_bf16.h>
#include <math.h>

#define B_  2
#define S_  2048
#define H_  16
#define D_  1024
#define DK_ 64

typedef __attribute__((ext_vector_type(8))) short bf16x8;   // 8 bf16 = 4 VGPRs
typedef __attribute__((ext_vector_type(8))) unsigned short ushort8v;
typedef __attribute__((ext_vector_type(4))) float f32x4;

__device__ __forceinline__ unsigned short f2bf(float f) {
  unsigned u = __float_as_uint(f);
  unsigned r = (u + 0x7FFFu + ((u >> 16) & 1u)) >> 16;   // RNE
  return (unsigned short)r;
}
__device__ __forceinline__ float bf2f(unsigned short h) {
  return __uint_as_float((unsigned)h << 16);
}
// truncation pack: two fp32 -> packed bf16x2 (P in [0,1]; bias ~2^-9, OK)
__device__ __forceinline__ unsigned pack_trunc(float lo, float hi) {
  return (__float_as_uint(lo) >> 16) | (__float_as_uint(hi) & 0xffff0000u);
}
__device__ __forceinline__ float fast_exp2(float x) {
#if __has_builtin(__builtin_amdgcn_exp2f)
  return __builtin_amdgcn_exp2f(x);
#else
  return __expf(x * 0.69314718056f);
#endif
}
// async global->LDS, 16B/lane. LDS dest = wave-uniform base + lane*16.
__device__ __forceinline__ void gload_lds16(const unsigned short* g,
                                            unsigned short* l) {
  __builtin_amdgcn_global_load_lds(
      (const __attribute__((address_space(1))) unsigned int*)(const void*)g,
      (__attribute__((address_space(3))) unsigned int*)(void*)l, 16, 0, 0);
}

// ---------------------------------------------------------------------------
// Cast fp32 -> bf16 for x and the four weights. blockIdx.y selects tensor.
// ---------------------------------------------------------------------------
__global__ __launch_bounds__(256)
void cast5_bf16(const float* __restrict__ x,  const float* __restrict__ wq,
                const float* __restrict__ wk, const float* __restrict__ wv,
                const float* __restrict__ wo,
                unsigned short* __restrict__ xb,  unsigned short* __restrict__ wqb,
                unsigned short* __restrict__ wkb, unsigned short* __restrict__ wvb,
                unsigned short* __restrict__ wob)
{
  const int z = blockIdx.y;
  const float* s; unsigned short* d; int nblk;
  switch (z) {
    case 0: s = x;  d = xb;  nblk = 2048; break;
    case 1: s = wq; d = wqb; nblk = 512;  break;
    case 2: s = wk; d = wkb; nblk = 512;  break;
    case 3: s = wv; d = wvb; nblk = 512;  break;
    default: s = wo; d = wob; nblk = 512; break;
  }
  if ((int)blockIdx.x >= nblk) return;
  size_t i0 = ((size_t)blockIdx.x * 256 + threadIdx.x) * 8;
  float4 v0 = *(const float4*)(s + i0);
  float4 v1 = *(const float4*)(s + i0 + 4);
  ushort8v o;
  o[0] = f2bf(v0.x); o[1] = f2bf(v0.y); o[2] = f2bf(v0.z); o[3] = f2bf(v0.w);
  o[4] = f2bf(v1.x); o[5] = f2bf(v1.y); o[6] = f2bf(v1.z); o[7] = f2bf(v1.w);
  *(ushort8v*)(d + i0) = o;
}

// ---------------------------------------------------------------------------
// bf16 MFMA GEMM NT (m97 structure), XOR-swizzled LDS slots.
// ksplit==0: blockIdx.z selects (W,C) triple (fused QKV), full K.
// ksplit>0 : W0/C0 only; blockIdx.z selects K-slice; fp32 atomicAdd epilogue
//            (C must be pre-zeroed).
// ---------------------------------------------------------------------------
__global__ __launch_bounds__(256)
void gemm_mfma(const unsigned short* __restrict__ A,
               const unsigned short* __restrict__ W0,
               const unsigned short* __restrict__ W1,
               const unsigned short* __restrict__ W2,
               void* __restrict__ C0v, void* __restrict__ C1v,
               void* __restrict__ C2v,
               int M, int N, int K, int bf16_out, int ksplit)
{
  const unsigned short* W;
  void* Cv;
  int kbeg, kend;
  if (ksplit) {
    W = W0; Cv = C0v;
    kbeg = blockIdx.z * (K / ksplit);
    kend = kbeg + K / ksplit;
  } else {
    W  = (blockIdx.z == 0) ? W0 : (blockIdx.z == 1) ? W1 : W2;
    Cv = (blockIdx.z == 0) ? C0v : (blockIdx.z == 1) ? C1v : C2v;
    kbeg = 0; kend = K;
  }

  __shared__ unsigned short As[128 * 32];
  __shared__ unsigned short Bs[128 * 32];

  const int tid   = threadIdx.x;
  const int wave  = tid >> 6;
  const int lane  = tid & 63;
  const int quad  = lane >> 4;
  const int col16 = lane & 15;
  const int row0  = blockIdx.y * 128;
  const int col0  = blockIdx.x * 128;
  const int wr    = (wave >> 1) * 64;
  const int wc    = (wave & 1) * 64;

  const int srow = wave * 16 + (lane >> 2);
  const int scol = ((lane & 3) ^ ((lane >> 2) & 3)) * 8;   // XOR swizzle
  const unsigned short* gA = A + (size_t)(row0 + srow) * K + scol;
  const unsigned short* gB = W + (size_t)(col0 + srow) * K + scol;
  unsigned short* lA0 = &As[(wave * 16) * 32];
  unsigned short* lA1 = &As[(wave * 16 + 64) * 32];
  unsigned short* lB0 = &Bs[(wave * 16) * 32];
  unsigned short* lB1 = &Bs[(wave * 16 + 64) * 32];

  f32x4 acc[4][4];
  #pragma unroll
  for (int mt = 0; mt < 4; ++mt)
    #pragma unroll
    for (int nt = 0; nt < 4; ++nt)
      #pragma unroll
      for (int r = 0; r < 4; ++r) acc[mt][nt][r] = 0.f;

  const int jx = (quad ^ (col16 & 3)) * 8;   // swizzled frag octet

  for (int k0 = kbeg; k0 < kend; k0 += 32) {
    __syncthreads();
    gload_lds16(gA + k0,                  lA0);
    gload_lds16(gA + (size_t)64 * K + k0, lA1);
    gload_lds16(gB + k0,                  lB0);
    gload_lds16(gB + (size_t)64 * K + k0, lB1);
    __syncthreads();

    bf16x8 af[4], bfr[4];
    #pragma unroll
    for (int mt = 0; mt < 4; ++mt)
      af[mt] = *(const bf16x8*)&As[(wr + mt * 16 + col16) * 32 + jx];
    #pragma unroll
    for (int nt = 0; nt < 4; ++nt)
      bfr[nt] = *(const bf16x8*)&Bs[(wc + nt * 16 + col16) * 32 + jx];

    #pragma unroll
    for (int mt = 0; mt < 4; ++mt)
      #pragma unroll
      for (int nt = 0; nt < 4; ++nt)
        acc[mt][nt] = __builtin_amdgcn_mfma_f32_16x16x32_bf16(
            af[mt], bfr[nt], acc[mt][nt], 0, 0, 0);
  }

  #pragma unroll
  for (int mt = 0; mt < 4; ++mt)
    #pragma unroll
    for (int r = 0; r < 4; ++r) {
      int row = row0 + wr + mt * 16 + quad * 4 + r;
      #pragma unroll
      for (int nt = 0; nt < 4; ++nt) {
        int col = col0 + wc + nt * 16 + col16;
        if (ksplit)
          atomicAdd((float*)Cv + (size_t)row * N + col, acc[mt][nt][r]);
        else if (bf16_out)
          ((unsigned short*)Cv)[(size_t)row * N + col] = f2bf(acc[mt][nt][r]);
        else
          ((float*)Cv)[(size_t)row * N + col] = acc[mt][nt][r];
      }
    }
}

// ---------------------------------------------------------------------------
// RoPE in-place on bf16 Q / K. Q additionally pre-scaled by 0.125*log2(e)
// so attention scores come out in the exp2 domain, pre-scaled.
// ---------------------------------------------------------------------------
__global__ __launch_bounds__(256)
void rope_bf16(unsigned short* __restrict__ q, unsigned short* __restrict__ k,
               const int* __restrict__ pos)
{
  int t = blockIdx.x * 256 + threadIdx.x;        // pair id
  const int isQ = (blockIdx.y == 0);
  unsigned short* buf = isQ ? q : k;
  const float qs = isQ ? 0.1803368801111204f : 1.0f;  // 0.125*log2(e)
  int i  = t & 31;
  int s  = (t >> 9) & 2047;
  int b  = t >> 20;
  int p  = pos[(b << 11) | s];
  float freq = __expf(-0.2878231366f * (float)i);  // 10000^(-2i/64)
  float ang  = (float)p * freq;
  float sn, cs;
  sincosf(ang, &sn, &cs);
  size_t off = ((size_t)(t >> 5) << 6) + 2 * (size_t)i;
  ushort2 v = *(ushort2*)(buf + off);
  float x = bf2f(v.x), y = bf2f(v.y);
  ushort2 r;
  r.x = f2bf((x * cs - y * sn) * qs);
  r.y = f2bf((x * sn + y * cs) * qs);
  *(ushort2*)(buf + off) = r;
}

// ---------------------------------------------------------------------------
// V transpose: vh bf16 [B,S,D] (head-sliced) -> vt bf16 [B*H, dk=64, S].
// ---------------------------------------------------------------------------
__global__ __launch_bounds__(256)
void transpose_v(const unsigned short* __restrict__ vh,
                 unsigned short* __restrict__ vt)
{
  __shared__ unsigned short T[64][70];
  const int s0  = blockIdx.x * 64;
  const int bh  = blockIdx.y;
  const int b   = bh >> 4, h = bh & 15;
  const int tid = threadIdx.x;

  #pragma unroll
  for (int p = 0; p < 2; ++p) {
    int idx = tid + p * 256;
    int s   = idx >> 3;
    int c8  = (idx & 7) * 8;
    *(bf16x8*)&T[s][c8] =
        *(const bf16x8*)(vh + (size_t)b * S_ * D_ + (size_t)(s0 + s) * D_ +
                         h * DK_ + c8);
  }
  __syncthreads();
  #pragma unroll
  for (int p = 0; p < 2; ++p) {
    int idx = tid + p * 256;
    int d   = idx >> 3;
    int s8  = (idx & 7) * 8;
    unsigned short tmp[8];
    #pragma unroll
    for (int j = 0; j < 8; ++j) tmp[j] = T[s8 + j][d];
    *(bf16x8*)(vt + ((size_t)bh * DK_ + d) * S_ + s0 + s8) = *(bf16x8*)tmp;
  }
}

// ---------------------------------------------------------------------------
// Softmax + P-pack for one side. st in S^T C-layout (q = lane&15).
// Returns P B-fragments via Pl LDS roundtrip.
// ---------------------------------------------------------------------------
__device__ __forceinline__ void softmax_pack(
    f32x4* st, f32x4* Oacc, float& m_i, float& l_i,
    unsigned short (* __restrict__ Pl)[72],
    int quad, int col, int qlocal, bool diag, bf16x8& pf0, bf16x8& pf1)
{
  if (diag) {
    #pragma unroll
    for (int nb = 0; nb < 4; ++nb)
      #pragma unroll
      for (int r = 0; r < 4; ++r)
        if (nb * 16 + quad * 4 + r > qlocal) st[nb][r] = -1e30f;
  }

  float vmax = -1e30f;
  #pragma unroll
  for (int nb = 0; nb < 4; ++nb)
    #pragma unroll
    for (int r = 0; r < 4; ++r) vmax = fmaxf(vmax, st[nb][r]);
  vmax = fmaxf(vmax, __shfl_xor(vmax, 16));
  vmax = fmaxf(vmax, __shfl_xor(vmax, 32));

  float mnew  = fmaxf(m_i, vmax);
  float alpha = fast_exp2(m_i - mnew);
  float rsum  = 0.f;
  #pragma unroll
  for (int nb = 0; nb < 4; ++nb)
    #pragma unroll
    for (int r = 0; r < 4; ++r) {
      float pv = fast_exp2(st[nb][r] - mnew);
      st[nb][r] = pv;
      rsum += pv;
    }
  rsum += __shfl_xor(rsum, 16);
  rsum += __shfl_xor(rsum, 32);
  m_i = mnew;
  l_i = l_i * alpha + rsum;
  #pragma unroll
  for (int nb = 0; nb < 4; ++nb)
    #pragma unroll
    for (int r = 0; r < 4; ++r) Oacc[nb][r] *= alpha;

  #pragma unroll
  for (int nb = 0; nb < 4; ++nb) {
    uint2 pk;
    pk.x = pack_trunc(st[nb][0], st[nb][1]);
    pk.y = pack_trunc(st[nb][2], st[nb][3]);
    *(uint2*)&Pl[col][nb * 16 + quad * 4] = pk;
  }
  pf0 = *(const bf16x8*)&Pl[col][quad * 8];
  pf1 = *(const bf16x8*)&Pl[col][32 + quad * 8];
}

// ---------------------------------------------------------------------------
// Paired MFMA flash attention: block handles q-tiles (i, 31-i) of one bh.
// K/V fragments loaded ONCE per kt and shared across both sides.
// ---------------------------------------------------------------------------
__global__ __launch_bounds__(256)
void attn_mfma(const unsigned short* __restrict__ Q,
               const unsigned short* __restrict__ K,
               const unsigned short* __restrict__ Vt,
               unsigned short* __restrict__ O)
{
  const int qtA  = blockIdx.x;        // 0..15
  const int qtB  = 31 - qtA;
  const int bh   = blockIdx.y;
  const int b    = bh >> 4, h = bh & 15;
  const int tid  = threadIdx.x;
  const int wave = tid >> 6;
  const int lane = tid & 63;
  const int quad = lane >> 4;
  const int col  = lane & 15;
  const int qlocal = wave * 16 + col;

  __shared__ unsigned short Ks[512 * 8];     // swizzled 16B slots
  __shared__ unsigned short Vs[512 * 8];
  __shared__ unsigned short PlA[4][16][72];
  __shared__ unsigned short PlB[4][16][72];

  const size_t qkbase = (size_t)b * S_ * D_ + (size_t)h * DK_;
  const size_t vtbase = (size_t)bh * DK_ * S_;

  const int qrowA = qtA * 64 + qlocal;
  const int qrowB = qtB * 64 + qlocal;
  bf16x8 qfA[2], qfB[2];
  qfA[0] = *(const bf16x8*)(Q + qkbase + (size_t)qrowA * D_ + quad * 8);
  qfA[1] = *(const bf16x8*)(Q + qkbase + (size_t)qrowA * D_ + 32 + quad * 8);
  qfB[0] = *(const bf16x8*)(Q + qkbase + (size_t)qrowB * D_ + quad * 8);
  qfB[1] = *(const bf16x8*)(Q + qkbase + (size_t)qrowB * D_ + 32 + quad * 8);

  // staging source (slot = p*256 + tid): row = p*32 + (tid>>3), octet sj
  const int sr = tid >> 3;
  const int sj = (tid & 7) ^ (sr & 7);
  const unsigned short* gK = K + qkbase + (size_t)sr * D_ + sj * 8;
  const unsigned short* gV = Vt + vtbase + (size_t)sr * S_ + sj * 8;
  unsigned short* ldsK[2] = { &Ks[(wave * 64) * 8], &Ks[(256 + wave * 64) * 8] };
  unsigned short* ldsV[2] = { &Vs[(wave * 64) * 8], &Vs[(256 + wave * 64) * 8] };

  f32x4 OaccA[4], OaccB[4];
  #pragma unroll
  for (int nb = 0; nb < 4; ++nb)
    #pragma unroll
    for (int r = 0; r < 4; ++r) { OaccA[nb][r] = 0.f; OaccB[nb][r] = 0.f; }
  float mA = -1e30f, lA = 0.f, mB = -1e30f, lB = 0.f;

  const int jx = quad ^ (col & 7);   // swizzled octet for K/V frag reads

  for (int kt = 0; kt <= qtB; ++kt) {
    __syncthreads();   // previous iteration's frag reads done
    #pragma unroll
    for (int p = 0; p < 2; ++p) {
      gload_lds16(gK + (size_t)(kt * 64 + p * 32) * D_, ldsK[p]);
      gload_lds16(gV + (size_t)(p * 32) * S_ + kt * 64, ldsV[p]);
    }
    __syncthreads();   // staging visible

    const bool doA = (kt <= qtA);
    const bool diagB = (kt == qtB), diagA = (kt == qtA);

    // S^T = K·Q^T for both sides, sharing the K fragments
    f32x4 stA[4], stB[4];
    #pragma unroll
    for (int nb = 0; nb < 4; ++nb) {
      const int s0 = (nb * 16 + col) * 8 + jx;
      bf16x8 ka0 = *(const bf16x8*)(Ks + s0 * 8);
      bf16x8 ka1 = *(const bf16x8*)(Ks + (s0 ^ 4) * 8);
      f32x4 a = {0.f, 0.f, 0.f, 0.f};
      a = __builtin_amdgcn_mfma_f32_16x16x32_bf16(ka0, qfB[0], a, 0, 0, 0);
      a = __builtin_amdgcn_mfma_f32_16x16x32_bf16(ka1, qfB[1], a, 0, 0, 0);
      stB[nb] = a;
      if (doA) {
        f32x4 c = {0.f, 0.f, 0.f, 0.f};
        c = __builtin_amdgcn_mfma_f32_16x16x32_bf16(ka0, qfA[0], c, 0, 0, 0);
        c = __builtin_amdgcn_mfma_f32_16x16x32_bf16(ka1, qfA[1], c, 0, 0, 0);
        stA[nb] = c;
      }
    }

    bf16x8 pfB0, pfB1, pfA0, pfA1;
    softmax_pack(stB, OaccB, mB, lB, PlB[wave], quad, col, qlocal, diagB,
                 pfB0, pfB1);
    if (doA)
      softmax_pack(stA, OaccA, mA, lA, PlA[wave], quad, col, qlocal, diagA,
                   pfA0, pfA1);

    // O^T += V^T·P^T for both sides, sharing the V fragments
    #pragma unroll
    for (int nb = 0; nb < 4; ++nb) {
      const int s0 = (nb * 16 + col) * 8 + jx;
      bf16x8 va0 = *(const bf16x8*)(Vs + s0 * 8);
      bf16x8 va1 = *(const bf16x8*)(Vs + (s0 ^ 4) * 8);
      OaccB[nb] = __builtin_amdgcn_mfma_f32_16x16x32_bf16(va0, pfB0, OaccB[nb], 0, 0, 0);
      OaccB[nb] = __builtin_amdgcn_mfma_f32_16x16x32_bf16(va1, pfB1, OaccB[nb], 0, 0, 0);
      if (doA) {
        OaccA[nb] = __builtin_amdgcn_mfma_f32_16x16x32_bf16(va0, pfA0, OaccA[nb], 0, 0, 0);
        OaccA[nb] = __builtin_amdgcn_mfma_f32_16x16x32_bf16(va1, pfA1, OaccA[nb], 0, 0, 0);
      }
    }
  }

  const float invA = 1.0f / lA;
  const float invB = 1.0f / lB;
  #pragma unroll
  for (int nb = 0; nb < 4; ++nb) {
    int d = nb * 16 + quad * 4;
    ushort4 oa, ob;
    oa.x = f2bf(OaccA[nb][0] * invA); oa.y = f2bf(OaccA[nb][1] * invA);
    oa.z = f2bf(OaccA[nb][2] * invA); oa.w = f2bf(OaccA[nb][3] * invA);
    ob.x = f2bf(OaccB[nb][0] * invB); ob.y = f2bf(OaccB[nb][1] * invB);
    ob.z = f2bf(OaccB[nb][2] * invB); ob.w = f2bf(OaccB[nb][3] * invB);
    *(ushort4*)(O + (size_t)b * S_ * D_ + (size_t)qrowA * D_ + h * DK_ + d) = oa;
    *(ushort4*)(O + (size_t)b * S_ * D_ + (size_t)qrowB * D_ + h * DK_ + d) = ob;
  }
}

// ---------------------------------------------------------------------------
extern "C" void kernel_launch(void* const* d_in, const int* in_sizes, int n_in,
                              void* d_out, int out_size, void* d_ws, size_t ws_size,
                              hipStream_t stream)
{
  const float* x  = (const float*)d_in[0];
  const float* Wq = (const float*)d_in[1];
  const float* Wk = (const float*)d_in[2];
  const float* Wv = (const float*)d_in[3];
  const float* Wo = (const float*)d_in[4];
  const int*   tp = (const int*)d_in[5];
  float* out = (float*)d_out;

  const size_t NTOK = (size_t)B_ * S_ * D_;     // 4,194,304 elements
  const size_t NW   = (size_t)D_ * D_;          // 1,048,576
  unsigned short* qh  = (unsigned short*)d_ws;  // bf16 [B,S,D]
  unsigned short* kh  = qh + NTOK;
  unsigned short* vh  = kh + NTOK;              // later reused as ab
  unsigned short* vt  = vh + NTOK;              // bf16 [B*H, 64, S]
  unsigned short* xb  = vt + NTOK;              // bf16 [B,S,D]
  unsigned short* wqb = xb + NTOK;
  unsigned short* wkb = wqb + NW;
  unsigned short* wvb = wkb + NW;
  unsigned short* wob = wvb + NW;
  unsigned short* ab  = vh;                     // alias: vh dead after transpose

  const int M = B_ * S_;   // 4096
  const int N = D_;        // 1024
  const int K = D_;        // 1024

  // fp32 -> bf16 casts
  cast5_bf16<<<dim3(2048, 5), 256, 0, stream>>>(
      x, Wq, Wk, Wv, Wo, xb, wqb, wkb, wvb, wob);

  // QKV projections (MFMA) -> bf16
  gemm_mfma<<<dim3(N / 128, M / 128, 3), 256, 0, stream>>>(
      xb, wqb, wkb, wvb, qh, kh, vh, M, N, K, 1, 0);

  // RoPE on bf16 Q,K (Q pre-scaled by 0.125*log2e)
  rope_bf16<<<dim3((B_ * S_ * H_ * 32) / 256, 2), 256, 0, stream>>>(qh, kh, tp);

  // V -> V^T bf16
  transpose_v<<<dim3(S_ / 64, B_ * H_), 256, 0, stream>>>(vh, vt);

  // paired causal MFMA flash attention -> bf16 ab (overwrites vh)
  attn_mfma<<<dim3(16, B_ * H_), 256, 0, stream>>>(qh, kh, vt, ab);

  // output projection (MFMA, split-K=2, atomic fp32) -> out
  hipMemsetAsync(out, 0, (size_t)out_size * sizeof(float), stream);
  gemm_mfma<<<dim3(N / 128, M / 128, 2), 256, 0, stream>>>(
      ab, wob, wob, wob, out, out, out, M, N, K, 0, 2);
}

// Round 6
// 213.710 us; speedup vs baseline: 1.1356x; 1.1356x over previous
//
#include <hip/hip_runtime.h>
#include <hip/hip_bf16.h>
#include <math.h>

#define B_  2
#define S_  2048
#define H_  16
#define D_  1024
#define DK_ 64

typedef __attribute__((ext_vector_type(8))) short bf16x8;   // 8 bf16 = 4 VGPRs
typedef __attribute__((ext_vector_type(8))) unsigned short ushort8v;
typedef __attribute__((ext_vector_type(4))) float f32x4;

__device__ __forceinline__ unsigned short f2bf(float f) {
  unsigned u = __float_as_uint(f);
  unsigned r = (u + 0x7FFFu + ((u >> 16) & 1u)) >> 16;   // RNE
  return (unsigned short)r;
}
__device__ __forceinline__ float bf2f(unsigned short h) {
  return __uint_as_float((unsigned)h << 16);
}
// truncation pack: two fp32 -> packed bf16x2 (P>=0; relative err ~2^-8, OK)
__device__ __forceinline__ unsigned pack_trunc(float lo, float hi) {
  return (__float_as_uint(lo) >> 16) | (__float_as_uint(hi) & 0xffff0000u);
}
__device__ __forceinline__ float fast_exp2(float x) {
#if __has_builtin(__builtin_amdgcn_exp2f)
  return __builtin_amdgcn_exp2f(x);
#else
  return __expf(x * 0.69314718056f);
#endif
}
// async global->LDS, 16B/lane. LDS dest = wave-uniform base + lane*16.
__device__ __forceinline__ void gload_lds16(const unsigned short* g,
                                            unsigned short* l) {
  __builtin_amdgcn_global_load_lds(
      (const __attribute__((address_space(1))) unsigned int*)(const void*)g,
      (__attribute__((address_space(3))) unsigned int*)(void*)l, 16, 0, 0);
}

// ---------------------------------------------------------------------------
// Cast fp32 -> bf16 for x (2048 blocks) + 4 weights (512 blocks each).
// Exact 1D grid of 4096 blocks, no no-op launches.
// ---------------------------------------------------------------------------
__global__ __launch_bounds__(256)
void cast5_bf16(const float* __restrict__ x,  const float* __restrict__ wq,
                const float* __restrict__ wk, const float* __restrict__ wv,
                const float* __restrict__ wo,
                unsigned short* __restrict__ xb,  unsigned short* __restrict__ wqb,
                unsigned short* __restrict__ wkb, unsigned short* __restrict__ wvb,
                unsigned short* __restrict__ wob)
{
  const int idx = blockIdx.x;
  const float* s; unsigned short* d; int lblk;
  if (idx < 2048) { s = x; d = xb; lblk = idx; }
  else {
    int t = idx - 2048;
    int w = t >> 9;          // 0..3
    lblk  = t & 511;
    s = (w == 0) ? wq  : (w == 1) ? wk  : (w == 2) ? wv  : wo;
    d = (w == 0) ? wqb : (w == 1) ? wkb : (w == 2) ? wvb : wob;
  }
  size_t i0 = ((size_t)lblk * 256 + threadIdx.x) * 8;
  float4 v0 = *(const float4*)(s + i0);
  float4 v1 = *(const float4*)(s + i0 + 4);
  ushort8v o;
  o[0] = f2bf(v0.x); o[1] = f2bf(v0.y); o[2] = f2bf(v0.z); o[3] = f2bf(v0.w);
  o[4] = f2bf(v1.x); o[5] = f2bf(v1.y); o[6] = f2bf(v1.z); o[7] = f2bf(v1.w);
  *(ushort8v*)(d + i0) = o;
}

// ---------------------------------------------------------------------------
// bf16 MFMA GEMM NT (m97 structure), XOR-swizzled LDS slots.
// blockIdx.z selects (W,C) triple (fused QKV). bf16 or fp32 output.
// ---------------------------------------------------------------------------
__global__ __launch_bounds__(256)
void gemm_mfma(const unsigned short* __restrict__ A,
               const unsigned short* __restrict__ W0,
               const unsigned short* __restrict__ W1,
               const unsigned short* __restrict__ W2,
               void* __restrict__ C0v, void* __restrict__ C1v,
               void* __restrict__ C2v,
               int M, int N, int K, int bf16_out)
{
  const unsigned short* W = (blockIdx.z == 0) ? W0 : (blockIdx.z == 1) ? W1 : W2;
  void* Cv = (blockIdx.z == 0) ? C0v : (blockIdx.z == 1) ? C1v : C2v;

  __shared__ unsigned short As[128 * 32];
  __shared__ unsigned short Bs[128 * 32];

  const int tid   = threadIdx.x;
  const int wave  = tid >> 6;
  const int lane  = tid & 63;
  const int quad  = lane >> 4;
  const int col16 = lane & 15;
  const int row0  = blockIdx.y * 128;
  const int col0  = blockIdx.x * 128;
  const int wr    = (wave >> 1) * 64;
  const int wc    = (wave & 1) * 64;

  const int srow = wave * 16 + (lane >> 2);
  const int scol = ((lane & 3) ^ ((lane >> 2) & 3)) * 8;   // XOR swizzle
  const unsigned short* gA = A + (size_t)(row0 + srow) * K + scol;
  const unsigned short* gB = W + (size_t)(col0 + srow) * K + scol;
  unsigned short* lA0 = &As[(wave * 16) * 32];
  unsigned short* lA1 = &As[(wave * 16 + 64) * 32];
  unsigned short* lB0 = &Bs[(wave * 16) * 32];
  unsigned short* lB1 = &Bs[(wave * 16 + 64) * 32];

  f32x4 acc[4][4];
  #pragma unroll
  for (int mt = 0; mt < 4; ++mt)
    #pragma unroll
    for (int nt = 0; nt < 4; ++nt)
      #pragma unroll
      for (int r = 0; r < 4; ++r) acc[mt][nt][r] = 0.f;

  const int jx = (quad ^ (col16 & 3)) * 8;   // swizzled frag octet

  for (int k0 = 0; k0 < K; k0 += 32) {
    __syncthreads();
    gload_lds16(gA + k0,                  lA0);
    gload_lds16(gA + (size_t)64 * K + k0, lA1);
    gload_lds16(gB + k0,                  lB0);
    gload_lds16(gB + (size_t)64 * K + k0, lB1);
    __syncthreads();

    bf16x8 af[4], bfr[4];
    #pragma unroll
    for (int mt = 0; mt < 4; ++mt)
      af[mt] = *(const bf16x8*)&As[(wr + mt * 16 + col16) * 32 + jx];
    #pragma unroll
    for (int nt = 0; nt < 4; ++nt)
      bfr[nt] = *(const bf16x8*)&Bs[(wc + nt * 16 + col16) * 32 + jx];

    #pragma unroll
    for (int mt = 0; mt < 4; ++mt)
      #pragma unroll
      for (int nt = 0; nt < 4; ++nt)
        acc[mt][nt] = __builtin_amdgcn_mfma_f32_16x16x32_bf16(
            af[mt], bfr[nt], acc[mt][nt], 0, 0, 0);
  }

  #pragma unroll
  for (int mt = 0; mt < 4; ++mt)
    #pragma unroll
    for (int r = 0; r < 4; ++r) {
      int row = row0 + wr + mt * 16 + quad * 4 + r;
      #pragma unroll
      for (int nt = 0; nt < 4; ++nt) {
        int col = col0 + wc + nt * 16 + col16;
        if (bf16_out)
          ((unsigned short*)Cv)[(size_t)row * N + col] = f2bf(acc[mt][nt][r]);
        else
          ((float*)Cv)[(size_t)row * N + col] = acc[mt][nt][r];
      }
    }
}

// ---------------------------------------------------------------------------
// RoPE in-place on bf16 Q / K. Q additionally pre-scaled by 0.125*log2(e)
// so attention scores come out in the exp2 domain, pre-scaled.
// ---------------------------------------------------------------------------
__global__ __launch_bounds__(256)
void rope_bf16(unsigned short* __restrict__ q, unsigned short* __restrict__ k,
               const int* __restrict__ pos)
{
  int t = blockIdx.x * 256 + threadIdx.x;        // pair id
  const int isQ = (blockIdx.y == 0);
  unsigned short* buf = isQ ? q : k;
  const float qs = isQ ? 0.1803368801111204f : 1.0f;  // 0.125*log2(e)
  int i  = t & 31;
  int s  = (t >> 9) & 2047;
  int b  = t >> 20;
  int p  = pos[(b << 11) | s];
  float freq = __expf(-0.2878231366f * (float)i);  // 10000^(-2i/64)
  float ang  = (float)p * freq;
  float sn, cs;
  sincosf(ang, &sn, &cs);
  size_t off = ((size_t)(t >> 5) << 6) + 2 * (size_t)i;
  ushort2 v = *(ushort2*)(buf + off);
  float x = bf2f(v.x), y = bf2f(v.y);
  ushort2 r;
  r.x = f2bf((x * cs - y * sn) * qs);
  r.y = f2bf((x * sn + y * cs) * qs);
  *(ushort2*)(buf + off) = r;
}

// ---------------------------------------------------------------------------
// V transpose: vh bf16 [B,S,D] (head-sliced) -> vt bf16 [B*H, dk=64, S].
// ---------------------------------------------------------------------------
__global__ __launch_bounds__(256)
void transpose_v(const unsigned short* __restrict__ vh,
                 unsigned short* __restrict__ vt)
{
  __shared__ unsigned short T[64][70];
  const int s0  = blockIdx.x * 64;
  const int bh  = blockIdx.y;
  const int b   = bh >> 4, h = bh & 15;
  const int tid = threadIdx.x;

  #pragma unroll
  for (int p = 0; p < 2; ++p) {
    int idx = tid + p * 256;
    int s   = idx >> 3;
    int c8  = (idx & 7) * 8;
    *(bf16x8*)&T[s][c8] =
        *(const bf16x8*)(vh + (size_t)b * S_ * D_ + (size_t)(s0 + s) * D_ +
                         h * DK_ + c8);
  }
  __syncthreads();
  #pragma unroll
  for (int p = 0; p < 2; ++p) {
    int idx = tid + p * 256;
    int d   = idx >> 3;
    int s8  = (idx & 7) * 8;
    unsigned short tmp[8];
    #pragma unroll
    for (int j = 0; j < 8; ++j) tmp[j] = T[s8 + j][d];
    *(bf16x8*)(vt + ((size_t)bh * DK_ + d) * S_ + s0 + s8) = *(bf16x8*)tmp;
  }
}

// ---------------------------------------------------------------------------
// One tile-side of paired flash attention, FIXED-MAX softmax:
// scores are in the exp2 domain (Q pre-scaled by 0.125*log2e); the constant
// max M=24 is folded into the QK^T MFMA C-initializer, and cancels exactly
// in O = sum(p*v)/sum(p). No running max, no alpha rescale of Oacc.
// K/V in XOR-swizzled LDS slots: phys slot(r,j)=r*8+(j^(r&7)), 8-short slots.
// ---------------------------------------------------------------------------
__device__ __forceinline__ void attn_side(
    const unsigned short* __restrict__ Ks, const unsigned short* __restrict__ Vs,
    unsigned short (* __restrict__ Pl)[72],
    const bf16x8* qf, f32x4* Oacc, float& l_i,
    int quad, int col, int qlocal, bool diag)
{
  const int jx = quad ^ (col & 7);
  f32x4 st[4];
  #pragma unroll
  for (int nb = 0; nb < 4; ++nb) {
    const int s0 = (nb * 16 + col) * 8 + jx;
    bf16x8 ka0 = *(const bf16x8*)(Ks + s0 * 8);
    bf16x8 ka1 = *(const bf16x8*)(Ks + (s0 ^ 4) * 8);
    f32x4 a = {-24.f, -24.f, -24.f, -24.f};   // fixed-max bias in C-init
    a = __builtin_amdgcn_mfma_f32_16x16x32_bf16(ka0, qf[0], a, 0, 0, 0);
    a = __builtin_amdgcn_mfma_f32_16x16x32_bf16(ka1, qf[1], a, 0, 0, 0);
    st[nb] = a;
  }

  if (diag) {
    #pragma unroll
    for (int nb = 0; nb < 4; ++nb)
      #pragma unroll
      for (int r = 0; r < 4; ++r)
        if (nb * 16 + quad * 4 + r > qlocal) st[nb][r] = -1e30f;
  }

  float rsum = 0.f;
  #pragma unroll
  for (int nb = 0; nb < 4; ++nb)
    #pragma unroll
    for (int r = 0; r < 4; ++r) {
      float pv = fast_exp2(st[nb][r]);
      st[nb][r] = pv;
      rsum += pv;
    }
  rsum += __shfl_xor(rsum, 16);
  rsum += __shfl_xor(rsum, 32);
  l_i += rsum;

  #pragma unroll
  for (int nb = 0; nb < 4; ++nb) {
    uint2 pk;
    pk.x = pack_trunc(st[nb][0], st[nb][1]);
    pk.y = pack_trunc(st[nb][2], st[nb][3]);
    *(uint2*)&Pl[col][nb * 16 + quad * 4] = pk;
  }

  bf16x8 pf0 = *(const bf16x8*)&Pl[col][quad * 8];
  bf16x8 pf1 = *(const bf16x8*)&Pl[col][32 + quad * 8];
  #pragma unroll
  for (int nb = 0; nb < 4; ++nb) {
    const int s0 = (nb * 16 + col) * 8 + jx;
    bf16x8 va0 = *(const bf16x8*)(Vs + s0 * 8);
    bf16x8 va1 = *(const bf16x8*)(Vs + (s0 ^ 4) * 8);
    Oacc[nb] = __builtin_amdgcn_mfma_f32_16x16x32_bf16(va0, pf0, Oacc[nb], 0, 0, 0);
    Oacc[nb] = __builtin_amdgcn_mfma_f32_16x16x32_bf16(va1, pf1, Oacc[nb], 0, 0, 0);
  }
}

// ---------------------------------------------------------------------------
// Paired MFMA flash attention: block handles q-tiles (i, 31-i) of one bh.
// Uniform 33 tile-computations per block; two independent sides give ILP.
// ---------------------------------------------------------------------------
__global__ __launch_bounds__(256)
void attn_mfma(const unsigned short* __restrict__ Q,
               const unsigned short* __restrict__ K,
               const unsigned short* __restrict__ Vt,
               unsigned short* __restrict__ O)
{
  const int qtA  = blockIdx.x;        // 0..15
  const int qtB  = 31 - qtA;
  const int bh   = blockIdx.y;
  const int b    = bh >> 4, h = bh & 15;
  const int tid  = threadIdx.x;
  const int wave = tid >> 6;
  const int lane = tid & 63;
  const int quad = lane >> 4;
  const int col  = lane & 15;
  const int qlocal = wave * 16 + col;

  __shared__ unsigned short Ks[512 * 8];     // swizzled 16B slots
  __shared__ unsigned short Vs[512 * 8];
  __shared__ unsigned short PlA[4][16][72];
  __shared__ unsigned short PlB[4][16][72];

  const size_t qkbase = (size_t)b * S_ * D_ + (size_t)h * DK_;
  const size_t vtbase = (size_t)bh * DK_ * S_;

  const int qrowA = qtA * 64 + qlocal;
  const int qrowB = qtB * 64 + qlocal;
  bf16x8 qfA[2], qfB[2];
  qfA[0] = *(const bf16x8*)(Q + qkbase + (size_t)qrowA * D_ + quad * 8);
  qfA[1] = *(const bf16x8*)(Q + qkbase + (size_t)qrowA * D_ + 32 + quad * 8);
  qfB[0] = *(const bf16x8*)(Q + qkbase + (size_t)qrowB * D_ + quad * 8);
  qfB[1] = *(const bf16x8*)(Q + qkbase + (size_t)qrowB * D_ + 32 + quad * 8);

  // staging source (slot = p*256 + tid): row = p*32 + (tid>>3), octet sj
  const int sr = tid >> 3;
  const int sj = (tid & 7) ^ (sr & 7);
  const unsigned short* gK = K + qkbase + (size_t)sr * D_ + sj * 8;
  const unsigned short* gV = Vt + vtbase + (size_t)sr * S_ + sj * 8;
  unsigned short* ldsK[2] = { &Ks[(wave * 64) * 8], &Ks[(256 + wave * 64) * 8] };
  unsigned short* ldsV[2] = { &Vs[(wave * 64) * 8], &Vs[(256 + wave * 64) * 8] };

  f32x4 OaccA[4], OaccB[4];
  #pragma unroll
  for (int nb = 0; nb < 4; ++nb)
    #pragma unroll
    for (int r = 0; r < 4; ++r) { OaccA[nb][r] = 0.f; OaccB[nb][r] = 0.f; }
  float lA = 0.f, lB = 0.f;

  for (int kt = 0; kt <= qtB; ++kt) {
    __syncthreads();   // previous iteration's frag reads done
    #pragma unroll
    for (int p = 0; p < 2; ++p) {
      gload_lds16(gK + (size_t)(kt * 64 + p * 32) * D_, ldsK[p]);
      gload_lds16(gV + (size_t)(p * 32) * S_ + kt * 64, ldsV[p]);
    }
    __syncthreads();   // staging visible

    attn_side(Ks, Vs, PlB[wave], qfB, OaccB, lB, quad, col, qlocal,
              kt == qtB);
    if (kt <= qtA)
      attn_side(Ks, Vs, PlA[wave], qfA, OaccA, lA, quad, col, qlocal,
                kt == qtA);
  }

  const float invA = 1.0f / lA;
  const float invB = 1.0f / lB;
  #pragma unroll
  for (int nb = 0; nb < 4; ++nb) {
    int d = nb * 16 + quad * 4;
    ushort4 oa, ob;
    oa.x = f2bf(OaccA[nb][0] * invA); oa.y = f2bf(OaccA[nb][1] * invA);
    oa.z = f2bf(OaccA[nb][2] * invA); oa.w = f2bf(OaccA[nb][3] * invA);
    ob.x = f2bf(OaccB[nb][0] * invB); ob.y = f2bf(OaccB[nb][1] * invB);
    ob.z = f2bf(OaccB[nb][2] * invB); ob.w = f2bf(OaccB[nb][3] * invB);
    *(ushort4*)(O + (size_t)b * S_ * D_ + (size_t)qrowA * D_ + h * DK_ + d) = oa;
    *(ushort4*)(O + (size_t)b * S_ * D_ + (size_t)qrowB * D_ + h * DK_ + d) = ob;
  }
}

// ---------------------------------------------------------------------------
extern "C" void kernel_launch(void* const* d_in, const int* in_sizes, int n_in,
                              void* d_out, int out_size, void* d_ws, size_t ws_size,
                              hipStream_t stream)
{
  const float* x  = (const float*)d_in[0];
  const float* Wq = (const float*)d_in[1];
  const float* Wk = (const float*)d_in[2];
  const float* Wv = (const float*)d_in[3];
  const float* Wo = (const float*)d_in[4];
  const int*   tp = (const int*)d_in[5];
  float* out = (float*)d_out;

  const size_t NTOK = (size_t)B_ * S_ * D_;     // 4,194,304 elements
  const size_t NW   = (size_t)D_ * D_;          // 1,048,576
  unsigned short* qh  = (unsigned short*)d_ws;  // bf16 [B,S,D]
  unsigned short* kh  = qh + NTOK;
  unsigned short* vh  = kh + NTOK;              // later reused as ab
  unsigned short* vt  = vh + NTOK;              // bf16 [B*H, 64, S]
  unsigned short* xb  = vt + NTOK;              // bf16 [B,S,D]
  unsigned short* wqb = xb + NTOK;
  unsigned short* wkb = wqb + NW;
  unsigned short* wvb = wkb + NW;
  unsigned short* wob = wvb + NW;
  unsigned short* ab  = vh;                     // alias: vh dead after transpose

  const int M = B_ * S_;   // 4096
  const int N = D_;        // 1024
  const int K = D_;        // 1024

  // fp32 -> bf16 casts (exact 4096-block 1D grid)
  cast5_bf16<<<dim3(4096), 256, 0, stream>>>(
      x, Wq, Wk, Wv, Wo, xb, wqb, wkb, wvb, wob);

  // QKV projections (MFMA) -> bf16
  gemm_mfma<<<dim3(N / 128, M / 128, 3), 256, 0, stream>>>(
      xb, wqb, wkb, wvb, qh, kh, vh, M, N, K, 1);

  // RoPE on bf16 Q,K (Q pre-scaled by 0.125*log2e)
  rope_bf16<<<dim3((B_ * S_ * H_ * 32) / 256, 2), 256, 0, stream>>>(qh, kh, tp);

  // V -> V^T bf16
  transpose_v<<<dim3(S_ / 64, B_ * H_), 256, 0, stream>>>(vh, vt);

  // paired causal MFMA flash attention (fixed-max softmax) -> bf16 ab
  attn_mfma<<<dim3(16, B_ * H_), 256, 0, stream>>>(qh, kh, vt, ab);

  // output projection (MFMA) -> fp32 out
  gemm_mfma<<<dim3(N / 128, M / 128, 1), 256, 0, stream>>>(
      ab, wob, wob, wob, out, out, out, M, N, K, 0);
}

// Round 7
// 197.069 us; speedup vs baseline: 1.2315x; 1.0844x over previous
//
#include <hip/hip_runtime.h>
#include <hip/hip_bf16.h>
#include <math.h>

#define B_  2
#define S_  2048
#define H_  16
#define D_  1024
#define DK_ 64

typedef __attribute__((ext_vector_type(8))) short bf16x8;   // 8 bf16 = 4 VGPRs
typedef __attribute__((ext_vector_type(8))) unsigned short ushort8v;
typedef __attribute__((ext_vector_type(4))) float f32x4;

__device__ __forceinline__ unsigned short f2bf(float f) {
  unsigned u = __float_as_uint(f);
  unsigned r = (u + 0x7FFFu + ((u >> 16) & 1u)) >> 16;   // RNE
  return (unsigned short)r;
}
// truncation pack: two fp32 -> packed bf16x2 (P>=0; relative err ~2^-8, OK)
__device__ __forceinline__ unsigned pack_trunc(float lo, float hi) {
  return (__float_as_uint(lo) >> 16) | (__float_as_uint(hi) & 0xffff0000u);
}
__device__ __forceinline__ float fast_exp2(float x) {
#if __has_builtin(__builtin_amdgcn_exp2f)
  return __builtin_amdgcn_exp2f(x);
#else
  return __expf(x * 0.69314718056f);
#endif
}
// async global->LDS, 16B/lane. LDS dest = wave-uniform base + lane*16.
__device__ __forceinline__ void gload_lds16(const unsigned short* g,
                                            unsigned short* l) {
  __builtin_amdgcn_global_load_lds(
      (const __attribute__((address_space(1))) unsigned int*)(const void*)g,
      (__attribute__((address_space(3))) unsigned int*)(void*)l, 16, 0, 0);
}

// ---------------------------------------------------------------------------
// Cast fp32 -> bf16 for x (2048 blocks) + 4 weights (512 blocks each).
// ---------------------------------------------------------------------------
__global__ __launch_bounds__(256)
void cast5_bf16(const float* __restrict__ x,  const float* __restrict__ wq,
                const float* __restrict__ wk, const float* __restrict__ wv,
                const float* __restrict__ wo,
                unsigned short* __restrict__ xb,  unsigned short* __restrict__ wqb,
                unsigned short* __restrict__ wkb, unsigned short* __restrict__ wvb,
                unsigned short* __restrict__ wob)
{
  const int idx = blockIdx.x;
  const float* s; unsigned short* d; int lblk;
  if (idx < 2048) { s = x; d = xb; lblk = idx; }
  else {
    int t = idx - 2048;
    int w = t >> 9;          // 0..3
    lblk  = t & 511;
    s = (w == 0) ? wq  : (w == 1) ? wk  : (w == 2) ? wv  : wo;
    d = (w == 0) ? wqb : (w == 1) ? wkb : (w == 2) ? wvb : wob;
  }
  size_t i0 = ((size_t)lblk * 256 + threadIdx.x) * 8;
  float4 v0 = *(const float4*)(s + i0);
  float4 v1 = *(const float4*)(s + i0 + 4);
  ushort8v o;
  o[0] = f2bf(v0.x); o[1] = f2bf(v0.y); o[2] = f2bf(v0.z); o[3] = f2bf(v0.w);
  o[4] = f2bf(v1.x); o[5] = f2bf(v1.y); o[6] = f2bf(v1.z); o[7] = f2bf(v1.w);
  *(ushort8v*)(d + i0) = o;
}

// ---------------------------------------------------------------------------
// Fused QKV projection GEMM (m97 structure, 128x128 tile, BK=32, XOR-swizzled
// LDS). blockIdx.z: 0=Q, 1=K, 2=V.
// Epilogue fusions:
//   z<2 : RoPE applied to fp32 accs (pairs are adjacent lanes, shfl_xor(1)),
//         Q additionally scaled by 0.125*log2(e) for exp2-domain softmax.
//   z==2: V written directly transposed to vt[b*16+h][d][s] (ushort4 along s).
// ---------------------------------------------------------------------------
__global__ __launch_bounds__(256)
void gemm_qkv(const unsigned short* __restrict__ A,
              const unsigned short* __restrict__ W0,
              const unsigned short* __restrict__ W1,
              const unsigned short* __restrict__ W2,
              unsigned short* __restrict__ qh,
              unsigned short* __restrict__ kh,
              unsigned short* __restrict__ vt,
              const int* __restrict__ tp)
{
  const int z = blockIdx.z;
  const unsigned short* W = (z == 0) ? W0 : (z == 1) ? W1 : W2;

  __shared__ unsigned short As[128 * 32];
  __shared__ unsigned short Bs[128 * 32];

  const int tid   = threadIdx.x;
  const int wave  = tid >> 6;
  const int lane  = tid & 63;
  const int quad  = lane >> 4;
  const int col16 = lane & 15;
  const int row0  = blockIdx.y * 128;
  const int col0  = blockIdx.x * 128;
  const int wr    = (wave >> 1) * 64;
  const int wc    = (wave & 1) * 64;

  const int srow = wave * 16 + (lane >> 2);
  const int scol = ((lane & 3) ^ ((lane >> 2) & 3)) * 8;   // XOR swizzle
  const unsigned short* gA = A + (size_t)(row0 + srow) * D_ + scol;
  const unsigned short* gB = W + (size_t)(col0 + srow) * D_ + scol;
  unsigned short* lA0 = &As[(wave * 16) * 32];
  unsigned short* lA1 = &As[(wave * 16 + 64) * 32];
  unsigned short* lB0 = &Bs[(wave * 16) * 32];
  unsigned short* lB1 = &Bs[(wave * 16 + 64) * 32];

  f32x4 acc[4][4];
  #pragma unroll
  for (int mt = 0; mt < 4; ++mt)
    #pragma unroll
    for (int nt = 0; nt < 4; ++nt)
      #pragma unroll
      for (int r = 0; r < 4; ++r) acc[mt][nt][r] = 0.f;

  const int jx = (quad ^ (col16 & 3)) * 8;   // swizzled frag octet

  for (int k0 = 0; k0 < D_; k0 += 32) {
    __syncthreads();
    gload_lds16(gA + k0,                   lA0);
    gload_lds16(gA + (size_t)64 * D_ + k0, lA1);
    gload_lds16(gB + k0,                   lB0);
    gload_lds16(gB + (size_t)64 * D_ + k0, lB1);
    __syncthreads();

    bf16x8 af[4], bfr[4];
    #pragma unroll
    for (int mt = 0; mt < 4; ++mt)
      af[mt] = *(const bf16x8*)&As[(wr + mt * 16 + col16) * 32 + jx];
    #pragma unroll
    for (int nt = 0; nt < 4; ++nt)
      bfr[nt] = *(const bf16x8*)&Bs[(wc + nt * 16 + col16) * 32 + jx];

    #pragma unroll
    for (int mt = 0; mt < 4; ++mt)
      #pragma unroll
      for (int nt = 0; nt < 4; ++nt)
        acc[mt][nt] = __builtin_amdgcn_mfma_f32_16x16x32_bf16(
            af[mt], bfr[nt], acc[mt][nt], 0, 0, 0);
  }

  if (z == 2) {
    // V: write transposed, 4 tokens (s) per ushort4
    #pragma unroll
    for (int mt = 0; mt < 4; ++mt) {
      int row = row0 + wr + mt * 16 + quad * 4;
      int bb  = row >> 11;          // batch
      int sl  = row & (S_ - 1);     // seq pos of r=0
      #pragma unroll
      for (int nt = 0; nt < 4; ++nt) {
        int col = col0 + wc + nt * 16 + col16;
        int h = col >> 6, d = col & 63;
        ushort4 o;
        o.x = f2bf(acc[mt][nt][0]); o.y = f2bf(acc[mt][nt][1]);
        o.z = f2bf(acc[mt][nt][2]); o.w = f2bf(acc[mt][nt][3]);
        *(ushort4*)(vt + ((size_t)((bb << 4) + h) * DK_ + d) * S_ + sl) = o;
      }
    }
  } else {
    unsigned short* C = z ? kh : qh;
    const float qs = z ? 1.0f : 0.1803368801111204f;  // 0.125*log2(e) for Q
    const float sgn = (col16 & 1) ? 1.f : -1.f;       // even lane: re = v*c - o*s
    float freqr[4];
    #pragma unroll
    for (int nt = 0; nt < 4; ++nt) {
      int i = ((wc + nt * 16 + col16) & 63) >> 1;
      freqr[nt] = exp2f(-0.4152410118f * (float)i);   // 10000^(-2i/64)
    }
    #pragma unroll
    for (int mt = 0; mt < 4; ++mt)
      #pragma unroll
      for (int r = 0; r < 4; ++r) {
        int row = row0 + wr + mt * 16 + quad * 4 + r;
        float p = (float)tp[row];
        #pragma unroll
        for (int nt = 0; nt < 4; ++nt) {
          int col = col0 + wc + nt * 16 + col16;
          float ang = p * freqr[nt];
          float sn = __sinf(ang), cs = __cosf(ang);
          float val = acc[mt][nt][r];
          float oth = __shfl_xor(val, 1);
          C[(size_t)row * D_ + col] = f2bf((val * cs + oth * sgn * sn) * qs);
        }
      }
  }
}

// ---------------------------------------------------------------------------
// Wo projection GEMM, 64(M)x128(N) tile, BK=32 -> 512 blocks = 2/CU.
// 4 waves in 2x2 grid, each 32x64 patch (2x4 MFMA tiles). fp32 output.
// ---------------------------------------------------------------------------
__global__ __launch_bounds__(256)
void gemm_wo(const unsigned short* __restrict__ A,
             const unsigned short* __restrict__ W,
             float* __restrict__ C)
{
  __shared__ unsigned short As[64 * 32];
  __shared__ unsigned short Bs[128 * 32];

  const int tid   = threadIdx.x;
  const int wave  = tid >> 6;
  const int lane  = tid & 63;
  const int quad  = lane >> 4;
  const int col16 = lane & 15;
  const int row0  = blockIdx.y * 64;
  const int col0  = blockIdx.x * 128;
  const int wr    = (wave >> 1) * 32;
  const int wc    = (wave & 1) * 64;

  const int srow = wave * 16 + (lane >> 2);
  const int scol = ((lane & 3) ^ ((lane >> 2) & 3)) * 8;
  const unsigned short* gA = A + (size_t)(row0 + srow) * D_ + scol;
  const unsigned short* gB = W + (size_t)(col0 + srow) * D_ + scol;
  unsigned short* lA0 = &As[(wave * 16) * 32];
  unsigned short* lB0 = &Bs[(wave * 16) * 32];
  unsigned short* lB1 = &Bs[(wave * 16 + 64) * 32];

  f32x4 acc[2][4];
  #pragma unroll
  for (int mt = 0; mt < 2; ++mt)
    #pragma unroll
    for (int nt = 0; nt < 4; ++nt)
      #pragma unroll
      for (int r = 0; r < 4; ++r) acc[mt][nt][r] = 0.f;

  const int jx = (quad ^ (col16 & 3)) * 8;

  for (int k0 = 0; k0 < D_; k0 += 32) {
    __syncthreads();
    gload_lds16(gA + k0,                   lA0);
    gload_lds16(gB + k0,                   lB0);
    gload_lds16(gB + (size_t)64 * D_ + k0, lB1);
    __syncthreads();

    bf16x8 af[2], bfr[4];
    #pragma unroll
    for (int mt = 0; mt < 2; ++mt)
      af[mt] = *(const bf16x8*)&As[(wr + mt * 16 + col16) * 32 + jx];
    #pragma unroll
    for (int nt = 0; nt < 4; ++nt)
      bfr[nt] = *(const bf16x8*)&Bs[(wc + nt * 16 + col16) * 32 + jx];

    #pragma unroll
    for (int mt = 0; mt < 2; ++mt)
      #pragma unroll
      for (int nt = 0; nt < 4; ++nt)
        acc[mt][nt] = __builtin_amdgcn_mfma_f32_16x16x32_bf16(
            af[mt], bfr[nt], acc[mt][nt], 0, 0, 0);
  }

  #pragma unroll
  for (int mt = 0; mt < 2; ++mt)
    #pragma unroll
    for (int r = 0; r < 4; ++r) {
      int row = row0 + wr + mt * 16 + quad * 4 + r;
      #pragma unroll
      for (int nt = 0; nt < 4; ++nt) {
        int col = col0 + wc + nt * 16 + col16;
        C[(size_t)row * D_ + col] = acc[mt][nt][r];
      }
    }
}

// ---------------------------------------------------------------------------
// One tile-side of paired flash attention, FIXED-MAX softmax (exp2 domain,
// Q pre-scaled; constant max 24 folded into the QK^T MFMA C-initializer).
// K/V in XOR-swizzled LDS slots: phys slot(r,j)=r*8+(j^(r&7)), 8-short slots.
// ---------------------------------------------------------------------------
__device__ __forceinline__ void attn_side(
    const unsigned short* __restrict__ Ks, const unsigned short* __restrict__ Vs,
    unsigned short (* __restrict__ Pl)[72],
    const bf16x8* qf, f32x4* Oacc, float& l_i,
    int quad, int col, int qlocal, bool diag)
{
  const int jx = quad ^ (col & 7);
  f32x4 st[4];
  #pragma unroll
  for (int nb = 0; nb < 4; ++nb) {
    const int s0 = (nb * 16 + col) * 8 + jx;
    bf16x8 ka0 = *(const bf16x8*)(Ks + s0 * 8);
    bf16x8 ka1 = *(const bf16x8*)(Ks + (s0 ^ 4) * 8);
    f32x4 a = {-24.f, -24.f, -24.f, -24.f};   // fixed-max bias in C-init
    a = __builtin_amdgcn_mfma_f32_16x16x32_bf16(ka0, qf[0], a, 0, 0, 0);
    a = __builtin_amdgcn_mfma_f32_16x16x32_bf16(ka1, qf[1], a, 0, 0, 0);
    st[nb] = a;
  }

  if (diag) {
    #pragma unroll
    for (int nb = 0; nb < 4; ++nb)
      #pragma unroll
      for (int r = 0; r < 4; ++r)
        if (nb * 16 + quad * 4 + r > qlocal) st[nb][r] = -1e30f;
  }

  float rsum = 0.f;
  #pragma unroll
  for (int nb = 0; nb < 4; ++nb)
    #pragma unroll
    for (int r = 0; r < 4; ++r) {
      float pv = fast_exp2(st[nb][r]);
      st[nb][r] = pv;
      rsum += pv;
    }
  rsum += __shfl_xor(rsum, 16);
  rsum += __shfl_xor(rsum, 32);
  l_i += rsum;

  #pragma unroll
  for (int nb = 0; nb < 4; ++nb) {
    uint2 pk;
    pk.x = pack_trunc(st[nb][0], st[nb][1]);
    pk.y = pack_trunc(st[nb][2], st[nb][3]);
    *(uint2*)&Pl[col][nb * 16 + quad * 4] = pk;
  }

  bf16x8 pf0 = *(const bf16x8*)&Pl[col][quad * 8];
  bf16x8 pf1 = *(const bf16x8*)&Pl[col][32 + quad * 8];
  #pragma unroll
  for (int nb = 0; nb < 4; ++nb) {
    const int s0 = (nb * 16 + col) * 8 + jx;
    bf16x8 va0 = *(const bf16x8*)(Vs + s0 * 8);
    bf16x8 va1 = *(const bf16x8*)(Vs + (s0 ^ 4) * 8);
    Oacc[nb] = __builtin_amdgcn_mfma_f32_16x16x32_bf16(va0, pf0, Oacc[nb], 0, 0, 0);
    Oacc[nb] = __builtin_amdgcn_mfma_f32_16x16x32_bf16(va1, pf1, Oacc[nb], 0, 0, 0);
  }
}

// ---------------------------------------------------------------------------
// Paired MFMA flash attention: block handles q-tiles (i, 31-i) of one bh.
// ---------------------------------------------------------------------------
__global__ __launch_bounds__(256)
void attn_mfma(const unsigned short* __restrict__ Q,
               const unsigned short* __restrict__ K,
               const unsigned short* __restrict__ Vt,
               unsigned short* __restrict__ O)
{
  const int qtA  = blockIdx.x;        // 0..15
  const int qtB  = 31 - qtA;
  const int bh   = blockIdx.y;
  const int b    = bh >> 4, h = bh & 15;
  const int tid  = threadIdx.x;
  const int wave = tid >> 6;
  const int lane = tid & 63;
  const int quad = lane >> 4;
  const int col  = lane & 15;
  const int qlocal = wave * 16 + col;

  __shared__ unsigned short Ks[512 * 8];     // swizzled 16B slots
  __shared__ unsigned short Vs[512 * 8];
  __shared__ unsigned short PlA[4][16][72];
  __shared__ unsigned short PlB[4][16][72];

  const size_t qkbase = (size_t)b * S_ * D_ + (size_t)h * DK_;
  const size_t vtbase = (size_t)bh * DK_ * S_;

  const int qrowA = qtA * 64 + qlocal;
  const int qrowB = qtB * 64 + qlocal;
  bf16x8 qfA[2], qfB[2];
  qfA[0] = *(const bf16x8*)(Q + qkbase + (size_t)qrowA * D_ + quad * 8);
  qfA[1] = *(const bf16x8*)(Q + qkbase + (size_t)qrowA * D_ + 32 + quad * 8);
  qfB[0] = *(const bf16x8*)(Q + qkbase + (size_t)qrowB * D_ + quad * 8);
  qfB[1] = *(const bf16x8*)(Q + qkbase + (size_t)qrowB * D_ + 32 + quad * 8);

  // staging source (slot = p*256 + tid): row = p*32 + (tid>>3), octet sj
  const int sr = tid >> 3;
  const int sj = (tid & 7) ^ (sr & 7);
  const unsigned short* gK = K + qkbase + (size_t)sr * D_ + sj * 8;
  const unsigned short* gV = Vt + vtbase + (size_t)sr * S_ + sj * 8;
  unsigned short* ldsK[2] = { &Ks[(wave * 64) * 8], &Ks[(256 + wave * 64) * 8] };
  unsigned short* ldsV[2] = { &Vs[(wave * 64) * 8], &Vs[(256 + wave * 64) * 8] };

  f32x4 OaccA[4], OaccB[4];
  #pragma unroll
  for (int nb = 0; nb < 4; ++nb)
    #pragma unroll
    for (int r = 0; r < 4; ++r) { OaccA[nb][r] = 0.f; OaccB[nb][r] = 0.f; }
  float lA = 0.f, lB = 0.f;

  for (int kt = 0; kt <= qtB; ++kt) {
    __syncthreads();   // previous iteration's frag reads done
    #pragma unroll
    for (int p = 0; p < 2; ++p) {
      gload_lds16(gK + (size_t)(kt * 64 + p * 32) * D_, ldsK[p]);
      gload_lds16(gV + (size_t)(p * 32) * S_ + kt * 64, ldsV[p]);
    }
    __syncthreads();   // staging visible

    attn_side(Ks, Vs, PlB[wave], qfB, OaccB, lB, quad, col, qlocal,
              kt == qtB);
    if (kt <= qtA)
      attn_side(Ks, Vs, PlA[wave], qfA, OaccA, lA, quad, col, qlocal,
                kt == qtA);
  }

  const float invA = 1.0f / lA;
  const float invB = 1.0f / lB;
  #pragma unroll
  for (int nb = 0; nb < 4; ++nb) {
    int d = nb * 16 + quad * 4;
    ushort4 oa, ob;
    oa.x = f2bf(OaccA[nb][0] * invA); oa.y = f2bf(OaccA[nb][1] * invA);
    oa.z = f2bf(OaccA[nb][2] * invA); oa.w = f2bf(OaccA[nb][3] * invA);
    ob.x = f2bf(OaccB[nb][0] * invB); ob.y = f2bf(OaccB[nb][1] * invB);
    ob.z = f2bf(OaccB[nb][2] * invB); ob.w = f2bf(OaccB[nb][3] * invB);
    *(ushort4*)(O + (size_t)b * S_ * D_ + (size_t)qrowA * D_ + h * DK_ + d) = oa;
    *(ushort4*)(O + (size_t)b * S_ * D_ + (size_t)qrowB * D_ + h * DK_ + d) = ob;
  }
}

// ---------------------------------------------------------------------------
extern "C" void kernel_launch(void* const* d_in, const int* in_sizes, int n_in,
                              void* d_out, int out_size, void* d_ws, size_t ws_size,
                              hipStream_t stream)
{
  const float* x  = (const float*)d_in[0];
  const float* Wq = (const float*)d_in[1];
  const float* Wk = (const float*)d_in[2];
  const float* Wv = (const float*)d_in[3];
  const float* Wo = (const float*)d_in[4];
  const int*   tp = (const int*)d_in[5];
  float* out = (float*)d_out;

  const size_t NTOK = (size_t)B_ * S_ * D_;     // 4,194,304 elements
  const size_t NW   = (size_t)D_ * D_;          // 1,048,576
  unsigned short* qh  = (unsigned short*)d_ws;  // bf16 [B,S,D]
  unsigned short* kh  = qh + NTOK;
  unsigned short* vt  = kh + NTOK;              // bf16 [B*H, 64, S]
  unsigned short* xb  = vt + NTOK;              // bf16 [B,S,D]; reused as ab
  unsigned short* wqb = xb + NTOK;
  unsigned short* wkb = wqb + NW;
  unsigned short* wvb = wkb + NW;
  unsigned short* wob = wvb + NW;
  unsigned short* ab  = xb;                     // alias: xb dead after QKV gemm

  // fp32 -> bf16 casts
  cast5_bf16<<<dim3(4096), 256, 0, stream>>>(
      x, Wq, Wk, Wv, Wo, xb, wqb, wkb, wvb, wob);

  // fused QKV projection + RoPE + Q-scale + V-transpose
  gemm_qkv<<<dim3(D_ / 128, (B_ * S_) / 128, 3), 256, 0, stream>>>(
      xb, wqb, wkb, wvb, qh, kh, vt, tp);

  // paired causal MFMA flash attention (fixed-max softmax) -> bf16 ab
  attn_mfma<<<dim3(16, B_ * H_), 256, 0, stream>>>(qh, kh, vt, ab);

  // output projection, 64x128 tiles (512 blocks = 2/CU) -> fp32 out
  gemm_wo<<<dim3(D_ / 128, (B_ * S_) / 64), 256, 0, stream>>>(ab, wob, out);
}

// Round 8
// 192.402 us; speedup vs baseline: 1.2613x; 1.0243x over previous
//
#include <hip/hip_runtime.h>
#include <hip/hip_bf16.h>
#include <math.h>

#define B_  2
#define S_  2048
#define H_  16
#define D_  1024
#define DK_ 64

typedef __attribute__((ext_vector_type(8))) short bf16x8;   // 8 bf16 = 4 VGPRs
typedef __attribute__((ext_vector_type(8))) unsigned short ushort8v;
typedef __attribute__((ext_vector_type(4))) float f32x4;

__device__ __forceinline__ unsigned short f2bf(float f) {
  unsigned u = __float_as_uint(f);
  unsigned r = (u + 0x7FFFu + ((u >> 16) & 1u)) >> 16;   // RNE
  return (unsigned short)r;
}
// truncation pack: two fp32 -> packed bf16x2 (P>=0; relative err ~2^-8, OK)
__device__ __forceinline__ unsigned pack_trunc(float lo, float hi) {
  return (__float_as_uint(lo) >> 16) | (__float_as_uint(hi) & 0xffff0000u);
}
__device__ __forceinline__ float fast_exp2(float x) {
#if __has_builtin(__builtin_amdgcn_exp2f)
  return __builtin_amdgcn_exp2f(x);
#else
  return __expf(x * 0.69314718056f);
#endif
}
// async global->LDS, 16B/lane. LDS dest = wave-uniform base + lane*16.
__device__ __forceinline__ void gload_lds16(const unsigned short* g,
                                            unsigned short* l) {
  __builtin_amdgcn_global_load_lds(
      (const __attribute__((address_space(1))) unsigned int*)(const void*)g,
      (__attribute__((address_space(3))) unsigned int*)(void*)l, 16, 0, 0);
}

// ---------------------------------------------------------------------------
// Cast fp32 -> bf16 for x (2048 blocks) + 4 weights (512 blocks each).
// ---------------------------------------------------------------------------
__global__ __launch_bounds__(256)
void cast5_bf16(const float* __restrict__ x,  const float* __restrict__ wq,
                const float* __restrict__ wk, const float* __restrict__ wv,
                const float* __restrict__ wo,
                unsigned short* __restrict__ xb,  unsigned short* __restrict__ wqb,
                unsigned short* __restrict__ wkb, unsigned short* __restrict__ wvb,
                unsigned short* __restrict__ wob)
{
  const int idx = blockIdx.x;
  const float* s; unsigned short* d; int lblk;
  if (idx < 2048) { s = x; d = xb; lblk = idx; }
  else {
    int t = idx - 2048;
    int w = t >> 9;          // 0..3
    lblk  = t & 511;
    s = (w == 0) ? wq  : (w == 1) ? wk  : (w == 2) ? wv  : wo;
    d = (w == 0) ? wqb : (w == 1) ? wkb : (w == 2) ? wvb : wob;
  }
  size_t i0 = ((size_t)lblk * 256 + threadIdx.x) * 8;
  float4 v0 = *(const float4*)(s + i0);
  float4 v1 = *(const float4*)(s + i0 + 4);
  ushort8v o;
  o[0] = f2bf(v0.x); o[1] = f2bf(v0.y); o[2] = f2bf(v0.z); o[3] = f2bf(v0.w);
  o[4] = f2bf(v1.x); o[5] = f2bf(v1.y); o[6] = f2bf(v1.z); o[7] = f2bf(v1.w);
  *(ushort8v*)(d + i0) = o;
}

// ---------------------------------------------------------------------------
// Fused QKV projection GEMM (m97 structure, 128x128 tile, BK=32, XOR-swizzled
// LDS). blockIdx.z: 0=Q, 1=K, 2=V.
//   z<2 : A = x (rows = tokens, blockIdx.y), B = W (rows = channels,
//         blockIdx.x). Epilogue: RoPE on fp32 accs (pairs = adjacent lanes,
//         shfl_xor(1)); Q scaled by 0.125*log2(e). tp staged in LDS.
//   z==2: OPERAND SWAP — A = Wv (rows = channels, blockIdx.x), B = x
//         (rows = tokens, blockIdx.y), so C = V^T directly; vt stores are
//         coalesced along s (no scatter).
// ---------------------------------------------------------------------------
__global__ __launch_bounds__(256)
void gemm_qkv(const unsigned short* __restrict__ A0,
              const unsigned short* __restrict__ W0,
              const unsigned short* __restrict__ W1,
              const unsigned short* __restrict__ W2,
              unsigned short* __restrict__ qh,
              unsigned short* __restrict__ kh,
              unsigned short* __restrict__ vt,
              const int* __restrict__ tp)
{
  const int z = blockIdx.z;

  __shared__ unsigned short As[128 * 32];
  __shared__ unsigned short Bs[128 * 32];
  __shared__ int tps[128];

  const int tid   = threadIdx.x;
  const int wave  = tid >> 6;
  const int lane  = tid & 63;
  const int quad  = lane >> 4;
  const int col16 = lane & 15;
  const int wr    = (wave >> 1) * 64;
  const int wc    = (wave & 1) * 64;

  // z<2: rows = tokens (y), cols = channels (x); z==2: rows = channels (x),
  // cols = tokens (y).
  const int row0 = (z == 2) ? blockIdx.x * 128 : blockIdx.y * 128;
  const int col0 = (z == 2) ? blockIdx.y * 128 : blockIdx.x * 128;
  const unsigned short* Aptr = (z == 0) ? A0 : (z == 1) ? A0 : W2;
  const unsigned short* Bptr = (z == 0) ? W0 : (z == 1) ? W1 : A0;

  if (z < 2 && tid < 128) tps[tid] = tp[row0 + tid];

  const int srow = wave * 16 + (lane >> 2);
  const int scol = ((lane & 3) ^ ((lane >> 2) & 3)) * 8;   // XOR swizzle
  const unsigned short* gA = Aptr + (size_t)(row0 + srow) * D_ + scol;
  const unsigned short* gB = Bptr + (size_t)(col0 + srow) * D_ + scol;
  unsigned short* lA0 = &As[(wave * 16) * 32];
  unsigned short* lA1 = &As[(wave * 16 + 64) * 32];
  unsigned short* lB0 = &Bs[(wave * 16) * 32];
  unsigned short* lB1 = &Bs[(wave * 16 + 64) * 32];

  f32x4 acc[4][4];
  #pragma unroll
  for (int mt = 0; mt < 4; ++mt)
    #pragma unroll
    for (int nt = 0; nt < 4; ++nt)
      #pragma unroll
      for (int r = 0; r < 4; ++r) acc[mt][nt][r] = 0.f;

  const int jx = (quad ^ (col16 & 3)) * 8;   // swizzled frag octet

  for (int k0 = 0; k0 < D_; k0 += 32) {
    __syncthreads();
    gload_lds16(gA + k0,                   lA0);
    gload_lds16(gA + (size_t)64 * D_ + k0, lA1);
    gload_lds16(gB + k0,                   lB0);
    gload_lds16(gB + (size_t)64 * D_ + k0, lB1);
    __syncthreads();

    bf16x8 af[4], bfr[4];
    #pragma unroll
    for (int mt = 0; mt < 4; ++mt)
      af[mt] = *(const bf16x8*)&As[(wr + mt * 16 + col16) * 32 + jx];
    #pragma unroll
    for (int nt = 0; nt < 4; ++nt)
      bfr[nt] = *(const bf16x8*)&Bs[(wc + nt * 16 + col16) * 32 + jx];

    #pragma unroll
    for (int mt = 0; mt < 4; ++mt)
      #pragma unroll
      for (int nt = 0; nt < 4; ++nt)
        acc[mt][nt] = __builtin_amdgcn_mfma_f32_16x16x32_bf16(
            af[mt], bfr[nt], acc[mt][nt], 0, 0, 0);
  }

  if (z == 2) {
    // C = V^T: row = channel c, col = token t; lanes (col16) are consecutive
    // tokens -> coalesced ushort stores into vt[(b*16+h)*64+d][s].
    #pragma unroll
    for (int mt = 0; mt < 4; ++mt)
      #pragma unroll
      for (int r = 0; r < 4; ++r) {
        int c = row0 + wr + mt * 16 + quad * 4 + r;   // channel
        int h = c >> 6, d = c & 63;
        #pragma unroll
        for (int nt = 0; nt < 4; ++nt) {
          int t  = col0 + wc + nt * 16 + col16;       // token
          int bb = t >> 11, sl = t & (S_ - 1);
          vt[((size_t)((bb << 4) + h) * DK_ + d) * S_ + sl] =
              f2bf(acc[mt][nt][r]);
        }
      }
  } else {
    unsigned short* C = z ? kh : qh;
    const float qs = z ? 1.0f : 0.1803368801111204f;  // 0.125*log2(e) for Q
    const float sgn = (col16 & 1) ? 1.f : -1.f;       // even lane: re = v*c - o*s
    float freqr[4];
    #pragma unroll
    for (int nt = 0; nt < 4; ++nt) {
      int i = ((wc + nt * 16 + col16) & 63) >> 1;
      freqr[nt] = exp2f(-0.4152410118f * (float)i);   // 10000^(-2i/64)
    }
    #pragma unroll
    for (int mt = 0; mt < 4; ++mt)
      #pragma unroll
      for (int r = 0; r < 4; ++r) {
        int rl  = wr + mt * 16 + quad * 4 + r;
        int row = row0 + rl;
        float p = (float)tps[rl];
        #pragma unroll
        for (int nt = 0; nt < 4; ++nt) {
          int col = col0 + wc + nt * 16 + col16;
          float ang = p * freqr[nt];
          float sn = __sinf(ang), cs = __cosf(ang);
          float val = acc[mt][nt][r];
          float oth = __shfl_xor(val, 1);
          C[(size_t)row * D_ + col] = f2bf((val * cs + oth * sgn * sn) * qs);
        }
      }
  }
}

// ---------------------------------------------------------------------------
// Wo projection GEMM, 64(M)x128(N) tile, BK=32 -> 512 blocks = 2/CU.
// ---------------------------------------------------------------------------
__global__ __launch_bounds__(256)
void gemm_wo(const unsigned short* __restrict__ A,
             const unsigned short* __restrict__ W,
             float* __restrict__ C)
{
  __shared__ unsigned short As[64 * 32];
  __shared__ unsigned short Bs[128 * 32];

  const int tid   = threadIdx.x;
  const int wave  = tid >> 6;
  const int lane  = tid & 63;
  const int quad  = lane >> 4;
  const int col16 = lane & 15;
  const int row0  = blockIdx.y * 64;
  const int col0  = blockIdx.x * 128;
  const int wr    = (wave >> 1) * 32;
  const int wc    = (wave & 1) * 64;

  const int srow = wave * 16 + (lane >> 2);
  const int scol = ((lane & 3) ^ ((lane >> 2) & 3)) * 8;
  const unsigned short* gA = A + (size_t)(row0 + srow) * D_ + scol;
  const unsigned short* gB = W + (size_t)(col0 + srow) * D_ + scol;
  unsigned short* lA0 = &As[(wave * 16) * 32];
  unsigned short* lB0 = &Bs[(wave * 16) * 32];
  unsigned short* lB1 = &Bs[(wave * 16 + 64) * 32];

  f32x4 acc[2][4];
  #pragma unroll
  for (int mt = 0; mt < 2; ++mt)
    #pragma unroll
    for (int nt = 0; nt < 4; ++nt)
      #pragma unroll
      for (int r = 0; r < 4; ++r) acc[mt][nt][r] = 0.f;

  const int jx = (quad ^ (col16 & 3)) * 8;

  for (int k0 = 0; k0 < D_; k0 += 32) {
    __syncthreads();
    gload_lds16(gA + k0,                   lA0);
    gload_lds16(gB + k0,                   lB0);
    gload_lds16(gB + (size_t)64 * D_ + k0, lB1);
    __syncthreads();

    bf16x8 af[2], bfr[4];
    #pragma unroll
    for (int mt = 0; mt < 2; ++mt)
      af[mt] = *(const bf16x8*)&As[(wr + mt * 16 + col16) * 32 + jx];
    #pragma unroll
    for (int nt = 0; nt < 4; ++nt)
      bfr[nt] = *(const bf16x8*)&Bs[(wc + nt * 16 + col16) * 32 + jx];

    #pragma unroll
    for (int mt = 0; mt < 2; ++mt)
      #pragma unroll
      for (int nt = 0; nt < 4; ++nt)
        acc[mt][nt] = __builtin_amdgcn_mfma_f32_16x16x32_bf16(
            af[mt], bfr[nt], acc[mt][nt], 0, 0, 0);
  }

  #pragma unroll
  for (int mt = 0; mt < 2; ++mt)
    #pragma unroll
    for (int r = 0; r < 4; ++r) {
      int row = row0 + wr + mt * 16 + quad * 4 + r;
      #pragma unroll
      for (int nt = 0; nt < 4; ++nt) {
        int col = col0 + wc + nt * 16 + col16;
        C[(size_t)row * D_ + col] = acc[mt][nt][r];
      }
    }
}

// ---------------------------------------------------------------------------
// One 64-key tile-side of paired flash attention, FIXED-MAX softmax (exp2
// domain, Q pre-scaled; constant max 24 folded into the QK^T C-initializer).
// K/V in XOR-swizzled LDS slots: phys slot(r,j)=r*8+(j^(r&7)), 8-short slots.
// ---------------------------------------------------------------------------
__device__ __forceinline__ void attn_side(
    const unsigned short* __restrict__ Ks, const unsigned short* __restrict__ Vs,
    unsigned short (* __restrict__ Pl)[72],
    const bf16x8* qf, f32x4* Oacc, float& l_i,
    int quad, int col, int qlocal, bool diag)
{
  const int jx = quad ^ (col & 7);
  f32x4 st[4];
  #pragma unroll
  for (int nb = 0; nb < 4; ++nb) {
    const int s0 = (nb * 16 + col) * 8 + jx;
    bf16x8 ka0 = *(const bf16x8*)(Ks + s0 * 8);
    bf16x8 ka1 = *(const bf16x8*)(Ks + (s0 ^ 4) * 8);
    f32x4 a = {-24.f, -24.f, -24.f, -24.f};   // fixed-max bias in C-init
    a = __builtin_amdgcn_mfma_f32_16x16x32_bf16(ka0, qf[0], a, 0, 0, 0);
    a = __builtin_amdgcn_mfma_f32_16x16x32_bf16(ka1, qf[1], a, 0, 0, 0);
    st[nb] = a;
  }

  if (diag) {
    #pragma unroll
    for (int nb = 0; nb < 4; ++nb)
      #pragma unroll
      for (int r = 0; r < 4; ++r)
        if (nb * 16 + quad * 4 + r > qlocal) st[nb][r] = -1e30f;
  }

  float rsum = 0.f;
  #pragma unroll
  for (int nb = 0; nb < 4; ++nb)
    #pragma unroll
    for (int r = 0; r < 4; ++r) {
      float pv = fast_exp2(st[nb][r]);
      st[nb][r] = pv;
      rsum += pv;
    }
  rsum += __shfl_xor(rsum, 16);
  rsum += __shfl_xor(rsum, 32);
  l_i += rsum;

  #pragma unroll
  for (int nb = 0; nb < 4; ++nb) {
    uint2 pk;
    pk.x = pack_trunc(st[nb][0], st[nb][1]);
    pk.y = pack_trunc(st[nb][2], st[nb][3]);
    *(uint2*)&Pl[col][nb * 16 + quad * 4] = pk;
  }

  bf16x8 pf0 = *(const bf16x8*)&Pl[col][quad * 8];
  bf16x8 pf1 = *(const bf16x8*)&Pl[col][32 + quad * 8];
  #pragma unroll
  for (int nb = 0; nb < 4; ++nb) {
    const int s0 = (nb * 16 + col) * 8 + jx;
    bf16x8 va0 = *(const bf16x8*)(Vs + s0 * 8);
    bf16x8 va1 = *(const bf16x8*)(Vs + (s0 ^ 4) * 8);
    Oacc[nb] = __builtin_amdgcn_mfma_f32_16x16x32_bf16(va0, pf0, Oacc[nb], 0, 0, 0);
    Oacc[nb] = __builtin_amdgcn_mfma_f32_16x16x32_bf16(va1, pf1, Oacc[nb], 0, 0, 0);
  }
}

// ---------------------------------------------------------------------------
// Paired MFMA flash attention: block handles q-tiles (i, 31-i) of one bh.
// 128-key staging tiles (2 x 64-key sub-tiles per barrier) halve barrier
// count; attn_side operates on 64-key sub-tiles unchanged.
// ---------------------------------------------------------------------------
__global__ __launch_bounds__(256)
void attn_mfma(const unsigned short* __restrict__ Q,
               const unsigned short* __restrict__ K,
               const unsigned short* __restrict__ Vt,
               unsigned short* __restrict__ O)
{
  const int qtA  = blockIdx.x;        // 0..15
  const int qtB  = 31 - qtA;
  const int bh   = blockIdx.y;
  const int b    = bh >> 4, h = bh & 15;
  const int tid  = threadIdx.x;
  const int wave = tid >> 6;
  const int lane = tid & 63;
  const int quad = lane >> 4;
  const int col  = lane & 15;
  const int qlocal = wave * 16 + col;

  __shared__ unsigned short Ks[1024 * 8];    // 2 half-tiles x 512 swizzled slots
  __shared__ unsigned short Vs[1024 * 8];
  __shared__ unsigned short PlA[4][16][72];
  __shared__ unsigned short PlB[4][16][72];

  const size_t qkbase = (size_t)b * S_ * D_ + (size_t)h * DK_;
  const size_t vtbase = (size_t)bh * DK_ * S_;

  const int qrowA = qtA * 64 + qlocal;
  const int qrowB = qtB * 64 + qlocal;
  bf16x8 qfA[2], qfB[2];
  qfA[0] = *(const bf16x8*)(Q + qkbase + (size_t)qrowA * D_ + quad * 8);
  qfA[1] = *(const bf16x8*)(Q + qkbase + (size_t)qrowA * D_ + 32 + quad * 8);
  qfB[0] = *(const bf16x8*)(Q + qkbase + (size_t)qrowB * D_ + quad * 8);
  qfB[1] = *(const bf16x8*)(Q + qkbase + (size_t)qrowB * D_ + 32 + quad * 8);

  // staging source (slot = p*256 + tid): row = p*32 + (tid>>3), octet sj
  const int sr = tid >> 3;
  const int sj = (tid & 7) ^ (sr & 7);
  const unsigned short* gK = K + qkbase + (size_t)sr * D_ + sj * 8;
  const unsigned short* gV = Vt + vtbase + (size_t)sr * S_ + sj * 8;

  f32x4 OaccA[4], OaccB[4];
  #pragma unroll
  for (int nb = 0; nb < 4; ++nb)
    #pragma unroll
    for (int r = 0; r < 4; ++r) { OaccA[nb][r] = 0.f; OaccB[nb][r] = 0.f; }
  float lA = 0.f, lB = 0.f;

  const int nK128 = (qtB + 2) >> 1;   // 128-key tiles covering (qtB+1)*64 keys

  for (int m = 0; m < nK128; ++m) {
    __syncthreads();   // previous tile's frag reads done
    #pragma unroll
    for (int half = 0; half < 2; ++half) {
      const int kbase = m * 128 + half * 64;
      #pragma unroll
      for (int p = 0; p < 2; ++p) {
        gload_lds16(gK + (size_t)(kbase + p * 32) * D_,
                    &Ks[(size_t)half * 4096 + (size_t)(p * 256 + wave * 64) * 8]);
        gload_lds16(gV + (size_t)(p * 32) * S_ + kbase,
                    &Vs[(size_t)half * 4096 + (size_t)(p * 256 + wave * 64) * 8]);
      }
    }
    __syncthreads();   // staging visible

    #pragma unroll
    for (int half = 0; half < 2; ++half) {
      const int g = 2 * m + half;
      const unsigned short* KsH = Ks + half * 4096;
      const unsigned short* VsH = Vs + half * 4096;
      if (g <= qtB)
        attn_side(KsH, VsH, PlB[wave], qfB, OaccB, lB, quad, col, qlocal,
                  g == qtB);
      if (g <= qtA)
        attn_side(KsH, VsH, PlA[wave], qfA, OaccA, lA, quad, col, qlocal,
                  g == qtA);
    }
  }

  const float invA = 1.0f / lA;
  const float invB = 1.0f / lB;
  #pragma unroll
  for (int nb = 0; nb < 4; ++nb) {
    int d = nb * 16 + quad * 4;
    ushort4 oa, ob;
    oa.x = f2bf(OaccA[nb][0] * invA); oa.y = f2bf(OaccA[nb][1] * invA);
    oa.z = f2bf(OaccA[nb][2] * invA); oa.w = f2bf(OaccA[nb][3] * invA);
    ob.x = f2bf(OaccB[nb][0] * invB); ob.y = f2bf(OaccB[nb][1] * invB);
    ob.z = f2bf(OaccB[nb][2] * invB); ob.w = f2bf(OaccB[nb][3] * invB);
    *(ushort4*)(O + (size_t)b * S_ * D_ + (size_t)qrowA * D_ + h * DK_ + d) = oa;
    *(ushort4*)(O + (size_t)b * S_ * D_ + (size_t)qrowB * D_ + h * DK_ + d) = ob;
  }
}

// ---------------------------------------------------------------------------
extern "C" void kernel_launch(void* const* d_in, const int* in_sizes, int n_in,
                              void* d_out, int out_size, void* d_ws, size_t ws_size,
                              hipStream_t stream)
{
  const float* x  = (const float*)d_in[0];
  const float* Wq = (const float*)d_in[1];
  const float* Wk = (const float*)d_in[2];
  const float* Wv = (const float*)d_in[3];
  const float* Wo = (const float*)d_in[4];
  const int*   tp = (const int*)d_in[5];
  float* out = (float*)d_out;

  const size_t NTOK = (size_t)B_ * S_ * D_;     // 4,194,304 elements
  const size_t NW   = (size_t)D_ * D_;          // 1,048,576
  unsigned short* qh  = (unsigned short*)d_ws;  // bf16 [B,S,D]
  unsigned short* kh  = qh + NTOK;
  unsigned short* vt  = kh + NTOK;              // bf16 [B*H, 64, S]
  unsigned short* xb  = vt + NTOK;              // bf16 [B,S,D]; reused as ab
  unsigned short* wqb = xb + NTOK;
  unsigned short* wkb = wqb + NW;
  unsigned short* wvb = wkb + NW;
  unsigned short* wob = wvb + NW;
  unsigned short* ab  = xb;                     // alias: xb dead after QKV gemm

  // fp32 -> bf16 casts
  cast5_bf16<<<dim3(4096), 256, 0, stream>>>(
      x, Wq, Wk, Wv, Wo, xb, wqb, wkb, wvb, wob);

  // fused QKV projection + RoPE + Q-scale + direct-V^T (operand swap)
  gemm_qkv<<<dim3(D_ / 128, (B_ * S_) / 128, 3), 256, 0, stream>>>(
      xb, wqb, wkb, wvb, qh, kh, vt, tp);

  // paired causal MFMA flash attention (fixed-max softmax) -> bf16 ab
  attn_mfma<<<dim3(16, B_ * H_), 256, 0, stream>>>(qh, kh, vt, ab);

  // output projection, 64x128 tiles (512 blocks = 2/CU) -> fp32 out
  gemm_wo<<<dim3(D_ / 128, (B_ * S_) / 64), 256, 0, stream>>>(ab, wob, out);
}

// Round 9
// 184.575 us; speedup vs baseline: 1.3148x; 1.0424x over previous
//
#include <hip/hip_runtime.h>
#include <hip/hip_bf16.h>
#include <math.h>

#define B_  2
#define S_  2048
#define H_  16
#define D_  1024
#define DK_ 64

typedef __attribute__((ext_vector_type(8))) short bf16x8;   // 8 bf16 = 4 VGPRs
typedef __attribute__((ext_vector_type(8))) unsigned short ushort8v;
typedef __attribute__((ext_vector_type(4))) float f32x4;

__device__ __forceinline__ unsigned short f2bf(float f) {
  unsigned u = __float_as_uint(f);
  unsigned r = (u + 0x7FFFu + ((u >> 16) & 1u)) >> 16;   // RNE
  return (unsigned short)r;
}
// truncation pack: two fp32 -> packed bf16x2 (P>=0; relative err ~2^-8, OK)
__device__ __forceinline__ unsigned pack_trunc(float lo, float hi) {
  return (__float_as_uint(lo) >> 16) | (__float_as_uint(hi) & 0xffff0000u);
}
__device__ __forceinline__ float fast_exp2(float x) {
#if __has_builtin(__builtin_amdgcn_exp2f)
  return __builtin_amdgcn_exp2f(x);
#else
  return __expf(x * 0.69314718056f);
#endif
}
// async global->LDS, 16B/lane. LDS dest = wave-uniform base + lane*16.
__device__ __forceinline__ void gload_lds16(const unsigned short* g,
                                            unsigned short* l) {
  __builtin_amdgcn_global_load_lds(
      (const __attribute__((address_space(1))) unsigned int*)(const void*)g,
      (__attribute__((address_space(3))) unsigned int*)(void*)l, 16, 0, 0);
}

// ---------------------------------------------------------------------------
// Cast fp32 -> bf16 for x (2048 blocks) + 4 weights (512 blocks each).
// ---------------------------------------------------------------------------
__global__ __launch_bounds__(256)
void cast5_bf16(const float* __restrict__ x,  const float* __restrict__ wq,
                const float* __restrict__ wk, const float* __restrict__ wv,
                const float* __restrict__ wo,
                unsigned short* __restrict__ xb,  unsigned short* __restrict__ wqb,
                unsigned short* __restrict__ wkb, unsigned short* __restrict__ wvb,
                unsigned short* __restrict__ wob)
{
  const int idx = blockIdx.x;
  const float* s; unsigned short* d; int lblk;
  if (idx < 2048) { s = x; d = xb; lblk = idx; }
  else {
    int t = idx - 2048;
    int w = t >> 9;          // 0..3
    lblk  = t & 511;
    s = (w == 0) ? wq  : (w == 1) ? wk  : (w == 2) ? wv  : wo;
    d = (w == 0) ? wqb : (w == 1) ? wkb : (w == 2) ? wvb : wob;
  }
  size_t i0 = ((size_t)lblk * 256 + threadIdx.x) * 8;
  float4 v0 = *(const float4*)(s + i0);
  float4 v1 = *(const float4*)(s + i0 + 4);
  ushort8v o;
  o[0] = f2bf(v0.x); o[1] = f2bf(v0.y); o[2] = f2bf(v0.z); o[3] = f2bf(v0.w);
  o[4] = f2bf(v1.x); o[5] = f2bf(v1.y); o[6] = f2bf(v1.z); o[7] = f2bf(v1.w);
  *(ushort8v*)(d + i0) = o;
}

// ---------------------------------------------------------------------------
// Fused QKV projection GEMM, 128x128 tile, BK=64 (16 K-iterations -> half the
// barrier drains of BK=32). Row = 64 shorts = 128 B = exact bank wrap, so
// LDS uses a mod-8 XOR swizzle: phys octet = logical ^ (row & 7).
// blockIdx.z: 0=Q, 1=K, 2=V.
//   z<2 : A = x (rows=tokens, y), B = W (rows=channels, x). Epilogue RoPE on
//         fp32 accs (pairs = adjacent lanes, shfl_xor(1)); Q scaled by
//         0.125*log2(e). tp staged in LDS.
//   z==2: operand swap (A = Wv, B = x) -> C = V^T directly, coalesced stores.
// ---------------------------------------------------------------------------
__global__ __launch_bounds__(256)
void gemm_qkv(const unsigned short* __restrict__ A0,
              const unsigned short* __restrict__ W0,
              const unsigned short* __restrict__ W1,
              const unsigned short* __restrict__ W2,
              unsigned short* __restrict__ qh,
              unsigned short* __restrict__ kh,
              unsigned short* __restrict__ vt,
              const int* __restrict__ tp)
{
  const int z = blockIdx.z;

  __shared__ unsigned short As[128 * 64];   // 16 KB
  __shared__ unsigned short Bs[128 * 64];   // 16 KB
  __shared__ int tps[128];

  const int tid   = threadIdx.x;
  const int wave  = tid >> 6;
  const int lane  = tid & 63;
  const int quad  = lane >> 4;
  const int col16 = lane & 15;
  const int wr    = (wave >> 1) * 64;
  const int wc    = (wave & 1) * 64;

  const int row0 = (z == 2) ? blockIdx.x * 128 : blockIdx.y * 128;
  const int col0 = (z == 2) ? blockIdx.y * 128 : blockIdx.x * 128;
  const unsigned short* Aptr = (z == 2) ? W2 : A0;
  const unsigned short* Bptr = (z == 0) ? W0 : (z == 1) ? W1 : A0;

  if (z < 2 && tid < 128) tps[tid] = tp[row0 + tid];

  // staging: one issue = 4 KB = 32 rows x 128 B; wave covers 8 rows.
  // lane -> row (lane>>3), chunk (lane&7); phys chunk = c ^ (row&7).
  const int srow = wave * 8 + (lane >> 3);
  const int scol = ((lane & 7) ^ ((lane >> 3) & 7)) * 8;
  const unsigned short* gA = Aptr + (size_t)(row0 + srow) * D_ + scol;
  const unsigned short* gB = Bptr + (size_t)(col0 + srow) * D_ + scol;

  f32x4 acc[4][4];
  #pragma unroll
  for (int mt = 0; mt < 4; ++mt)
    #pragma unroll
    for (int nt = 0; nt < 4; ++nt)
      #pragma unroll
      for (int r = 0; r < 4; ++r) acc[mt][nt][r] = 0.f;

  for (int k0 = 0; k0 < D_; k0 += 64) {
    __syncthreads();
    #pragma unroll
    for (int p = 0; p < 4; ++p) {
      gload_lds16(gA + (size_t)(p * 32) * D_ + k0, &As[(p * 32 + wave * 8) * 64]);
      gload_lds16(gB + (size_t)(p * 32) * D_ + k0, &Bs[(p * 32 + wave * 8) * 64]);
    }
    __syncthreads();

    #pragma unroll
    for (int h = 0; h < 2; ++h) {
      const int jo = ((h * 4 + quad) ^ (col16 & 7)) * 8;
      bf16x8 af[4], bfr[4];
      #pragma unroll
      for (int mt = 0; mt < 4; ++mt)
        af[mt] = *(const bf16x8*)&As[(wr + mt * 16 + col16) * 64 + jo];
      #pragma unroll
      for (int nt = 0; nt < 4; ++nt)
        bfr[nt] = *(const bf16x8*)&Bs[(wc + nt * 16 + col16) * 64 + jo];

      #pragma unroll
      for (int mt = 0; mt < 4; ++mt)
        #pragma unroll
        for (int nt = 0; nt < 4; ++nt)
          acc[mt][nt] = __builtin_amdgcn_mfma_f32_16x16x32_bf16(
              af[mt], bfr[nt], acc[mt][nt], 0, 0, 0);
    }
  }

  if (z == 2) {
    // C = V^T: row = channel c, col = token t; lanes are consecutive tokens.
    #pragma unroll
    for (int mt = 0; mt < 4; ++mt)
      #pragma unroll
      for (int r = 0; r < 4; ++r) {
        int c = row0 + wr + mt * 16 + quad * 4 + r;   // channel
        int h = c >> 6, d = c & 63;
        #pragma unroll
        for (int nt = 0; nt < 4; ++nt) {
          int t  = col0 + wc + nt * 16 + col16;       // token
          int bb = t >> 11, sl = t & (S_ - 1);
          vt[((size_t)((bb << 4) + h) * DK_ + d) * S_ + sl] =
              f2bf(acc[mt][nt][r]);
        }
      }
  } else {
    unsigned short* C = z ? kh : qh;
    const float qs = z ? 1.0f : 0.1803368801111204f;  // 0.125*log2(e) for Q
    const float sgn = (col16 & 1) ? 1.f : -1.f;       // even lane: re = v*c - o*s
    float freqr[4];
    #pragma unroll
    for (int nt = 0; nt < 4; ++nt) {
      int i = ((wc + nt * 16 + col16) & 63) >> 1;
      freqr[nt] = exp2f(-0.4152410118f * (float)i);   // 10000^(-2i/64)
    }
    #pragma unroll
    for (int mt = 0; mt < 4; ++mt)
      #pragma unroll
      for (int r = 0; r < 4; ++r) {
        int rl  = wr + mt * 16 + quad * 4 + r;
        int row = row0 + rl;
        float p = (float)tps[rl];
        #pragma unroll
        for (int nt = 0; nt < 4; ++nt) {
          int col = col0 + wc + nt * 16 + col16;
          float ang = p * freqr[nt];
          float sn = __sinf(ang), cs = __cosf(ang);
          float val = acc[mt][nt][r];
          float oth = __shfl_xor(val, 1);
          C[(size_t)row * D_ + col] = f2bf((val * cs + oth * sgn * sn) * qs);
        }
      }
  }
}

// ---------------------------------------------------------------------------
// Wo projection GEMM, 64(M)x128(N) tile, BK=64 -> 512 blocks, 16 K-iters.
// Same mod-8 XOR-swizzled 128 B rows as gemm_qkv.
// ---------------------------------------------------------------------------
__global__ __launch_bounds__(256)
void gemm_wo(const unsigned short* __restrict__ A,
             const unsigned short* __restrict__ W,
             float* __restrict__ C)
{
  __shared__ unsigned short As[64 * 64];    // 8 KB
  __shared__ unsigned short Bs[128 * 64];   // 16 KB

  const int tid   = threadIdx.x;
  const int wave  = tid >> 6;
  const int lane  = tid & 63;
  const int quad  = lane >> 4;
  const int col16 = lane & 15;
  const int row0  = blockIdx.y * 64;
  const int col0  = blockIdx.x * 128;
  const int wr    = (wave >> 1) * 32;
  const int wc    = (wave & 1) * 64;

  const int srow = wave * 8 + (lane >> 3);
  const int scol = ((lane & 7) ^ ((lane >> 3) & 7)) * 8;
  const unsigned short* gA = A + (size_t)(row0 + srow) * D_ + scol;
  const unsigned short* gB = W + (size_t)(col0 + srow) * D_ + scol;

  f32x4 acc[2][4];
  #pragma unroll
  for (int mt = 0; mt < 2; ++mt)
    #pragma unroll
    for (int nt = 0; nt < 4; ++nt)
      #pragma unroll
      for (int r = 0; r < 4; ++r) acc[mt][nt][r] = 0.f;

  for (int k0 = 0; k0 < D_; k0 += 64) {
    __syncthreads();
    #pragma unroll
    for (int p = 0; p < 2; ++p)
      gload_lds16(gA + (size_t)(p * 32) * D_ + k0, &As[(p * 32 + wave * 8) * 64]);
    #pragma unroll
    for (int p = 0; p < 4; ++p)
      gload_lds16(gB + (size_t)(p * 32) * D_ + k0, &Bs[(p * 32 + wave * 8) * 64]);
    __syncthreads();

    #pragma unroll
    for (int h = 0; h < 2; ++h) {
      const int jo = ((h * 4 + quad) ^ (col16 & 7)) * 8;
      bf16x8 af[2], bfr[4];
      #pragma unroll
      for (int mt = 0; mt < 2; ++mt)
        af[mt] = *(const bf16x8*)&As[(wr + mt * 16 + col16) * 64 + jo];
      #pragma unroll
      for (int nt = 0; nt < 4; ++nt)
        bfr[nt] = *(const bf16x8*)&Bs[(wc + nt * 16 + col16) * 64 + jo];

      #pragma unroll
      for (int mt = 0; mt < 2; ++mt)
        #pragma unroll
        for (int nt = 0; nt < 4; ++nt)
          acc[mt][nt] = __builtin_amdgcn_mfma_f32_16x16x32_bf16(
              af[mt], bfr[nt], acc[mt][nt], 0, 0, 0);
    }
  }

  #pragma unroll
  for (int mt = 0; mt < 2; ++mt)
    #pragma unroll
    for (int r = 0; r < 4; ++r) {
      int row = row0 + wr + mt * 16 + quad * 4 + r;
      #pragma unroll
      for (int nt = 0; nt < 4; ++nt) {
        int col = col0 + wc + nt * 16 + col16;
        C[(size_t)row * D_ + col] = acc[mt][nt][r];
      }
    }
}

// ---------------------------------------------------------------------------
// One 64-key tile-side of paired flash attention, FIXED-MAX softmax (exp2
// domain, Q pre-scaled; constant max 24 folded into the QK^T C-initializer).
// K/V in XOR-swizzled LDS slots: phys slot(r,j)=r*8+(j^(r&7)), 8-short slots.
// ---------------------------------------------------------------------------
__device__ __forceinline__ void attn_side(
    const unsigned short* __restrict__ Ks, const unsigned short* __restrict__ Vs,
    unsigned short (* __restrict__ Pl)[72],
    const bf16x8* qf, f32x4* Oacc, float& l_i,
    int quad, int col, int qlocal, bool diag)
{
  const int jx = quad ^ (col & 7);
  f32x4 st[4];
  #pragma unroll
  for (int nb = 0; nb < 4; ++nb) {
    const int s0 = (nb * 16 + col) * 8 + jx;
    bf16x8 ka0 = *(const bf16x8*)(Ks + s0 * 8);
    bf16x8 ka1 = *(const bf16x8*)(Ks + (s0 ^ 4) * 8);
    f32x4 a = {-24.f, -24.f, -24.f, -24.f};   // fixed-max bias in C-init
    a = __builtin_amdgcn_mfma_f32_16x16x32_bf16(ka0, qf[0], a, 0, 0, 0);
    a = __builtin_amdgcn_mfma_f32_16x16x32_bf16(ka1, qf[1], a, 0, 0, 0);
    st[nb] = a;
  }

  if (diag) {
    #pragma unroll
    for (int nb = 0; nb < 4; ++nb)
      #pragma unroll
      for (int r = 0; r < 4; ++r)
        if (nb * 16 + quad * 4 + r > qlocal) st[nb][r] = -1e30f;
  }

  float rsum = 0.f;
  #pragma unroll
  for (int nb = 0; nb < 4; ++nb)
    #pragma unroll
    for (int r = 0; r < 4; ++r) {
      float pv = fast_exp2(st[nb][r]);
      st[nb][r] = pv;
      rsum += pv;
    }
  rsum += __shfl_xor(rsum, 16);
  rsum += __shfl_xor(rsum, 32);
  l_i += rsum;

  #pragma unroll
  for (int nb = 0; nb < 4; ++nb) {
    uint2 pk;
    pk.x = pack_trunc(st[nb][0], st[nb][1]);
    pk.y = pack_trunc(st[nb][2], st[nb][3]);
    *(uint2*)&Pl[col][nb * 16 + quad * 4] = pk;
  }

  bf16x8 pf0 = *(const bf16x8*)&Pl[col][quad * 8];
  bf16x8 pf1 = *(const bf16x8*)&Pl[col][32 + quad * 8];
  #pragma unroll
  for (int nb = 0; nb < 4; ++nb) {
    const int s0 = (nb * 16 + col) * 8 + jx;
    bf16x8 va0 = *(const bf16x8*)(Vs + s0 * 8);
    bf16x8 va1 = *(const bf16x8*)(Vs + (s0 ^ 4) * 8);
    Oacc[nb] = __builtin_amdgcn_mfma_f32_16x16x32_bf16(va0, pf0, Oacc[nb], 0, 0, 0);
    Oacc[nb] = __builtin_amdgcn_mfma_f32_16x16x32_bf16(va1, pf1, Oacc[nb], 0, 0, 0);
  }
}

// ---------------------------------------------------------------------------
// Paired MFMA flash attention: block handles q-tiles (i, 31-i) of one bh.
// 128-key staging tiles (2 x 64-key sub-tiles per barrier).
// ---------------------------------------------------------------------------
__global__ __launch_bounds__(256)
void attn_mfma(const unsigned short* __restrict__ Q,
               const unsigned short* __restrict__ K,
               const unsigned short* __restrict__ Vt,
               unsigned short* __restrict__ O)
{
  const int qtA  = blockIdx.x;        // 0..15
  const int qtB  = 31 - qtA;
  const int bh   = blockIdx.y;
  const int b    = bh >> 4, h = bh & 15;
  const int tid  = threadIdx.x;
  const int wave = tid >> 6;
  const int lane = tid & 63;
  const int quad = lane >> 4;
  const int col  = lane & 15;
  const int qlocal = wave * 16 + col;

  __shared__ unsigned short Ks[1024 * 8];    // 2 half-tiles x 512 swizzled slots
  __shared__ unsigned short Vs[1024 * 8];
  __shared__ unsigned short PlA[4][16][72];
  __shared__ unsigned short PlB[4][16][72];

  const size_t qkbase = (size_t)b * S_ * D_ + (size_t)h * DK_;
  const size_t vtbase = (size_t)bh * DK_ * S_;

  const int qrowA = qtA * 64 + qlocal;
  const int qrowB = qtB * 64 + qlocal;
  bf16x8 qfA[2], qfB[2];
  qfA[0] = *(const bf16x8*)(Q + qkbase + (size_t)qrowA * D_ + quad * 8);
  qfA[1] = *(const bf16x8*)(Q + qkbase + (size_t)qrowA * D_ + 32 + quad * 8);
  qfB[0] = *(const bf16x8*)(Q + qkbase + (size_t)qrowB * D_ + quad * 8);
  qfB[1] = *(const bf16x8*)(Q + qkbase + (size_t)qrowB * D_ + 32 + quad * 8);

  // staging source (slot = p*256 + tid): row = p*32 + (tid>>3), octet sj
  const int sr = tid >> 3;
  const int sj = (tid & 7) ^ (sr & 7);
  const unsigned short* gK = K + qkbase + (size_t)sr * D_ + sj * 8;
  const unsigned short* gV = Vt + vtbase + (size_t)sr * S_ + sj * 8;

  f32x4 OaccA[4], OaccB[4];
  #pragma unroll
  for (int nb = 0; nb < 4; ++nb)
    #pragma unroll
    for (int r = 0; r < 4; ++r) { OaccA[nb][r] = 0.f; OaccB[nb][r] = 0.f; }
  float lA = 0.f, lB = 0.f;

  const int nK128 = (qtB + 2) >> 1;   // 128-key tiles covering (qtB+1)*64 keys

  for (int m = 0; m < nK128; ++m) {
    __syncthreads();   // previous tile's frag reads done
    #pragma unroll
    for (int half = 0; half < 2; ++half) {
      const int kbase = m * 128 + half * 64;
      #pragma unroll
      for (int p = 0; p < 2; ++p) {
        gload_lds16(gK + (size_t)(kbase + p * 32) * D_,
                    &Ks[(size_t)half * 4096 + (size_t)(p * 256 + wave * 64) * 8]);
        gload_lds16(gV + (size_t)(p * 32) * S_ + kbase,
                    &Vs[(size_t)half * 4096 + (size_t)(p * 256 + wave * 64) * 8]);
      }
    }
    __syncthreads();   // staging visible

    #pragma unroll
    for (int half = 0; half < 2; ++half) {
      const int g = 2 * m + half;
      const unsigned short* KsH = Ks + half * 4096;
      const unsigned short* VsH = Vs + half * 4096;
      if (g <= qtB)
        attn_side(KsH, VsH, PlB[wave], qfB, OaccB, lB, quad, col, qlocal,
                  g == qtB);
      if (g <= qtA)
        attn_side(KsH, VsH, PlA[wave], qfA, OaccA, lA, quad, col, qlocal,
                  g == qtA);
    }
  }

  const float invA = 1.0f / lA;
  const float invB = 1.0f / lB;
  #pragma unroll
  for (int nb = 0; nb < 4; ++nb) {
    int d = nb * 16 + quad * 4;
    ushort4 oa, ob;
    oa.x = f2bf(OaccA[nb][0] * invA); oa.y = f2bf(OaccA[nb][1] * invA);
    oa.z = f2bf(OaccA[nb][2] * invA); oa.w = f2bf(OaccA[nb][3] * invA);
    ob.x = f2bf(OaccB[nb][0] * invB); ob.y = f2bf(OaccB[nb][1] * invB);
    ob.z = f2bf(OaccB[nb][2] * invB); ob.w = f2bf(OaccB[nb][3] * invB);
    *(ushort4*)(O + (size_t)b * S_ * D_ + (size_t)qrowA * D_ + h * DK_ + d) = oa;
    *(ushort4*)(O + (size_t)b * S_ * D_ + (size_t)qrowB * D_ + h * DK_ + d) = ob;
  }
}

// ---------------------------------------------------------------------------
extern "C" void kernel_launch(void* const* d_in, const int* in_sizes, int n_in,
                              void* d_out, int out_size, void* d_ws, size_t ws_size,
                              hipStream_t stream)
{
  const float* x  = (const float*)d_in[0];
  const float* Wq = (const float*)d_in[1];
  const float* Wk = (const float*)d_in[2];
  const float* Wv = (const float*)d_in[3];
  const float* Wo = (const float*)d_in[4];
  const int*   tp = (const int*)d_in[5];
  float* out = (float*)d_out;

  const size_t NTOK = (size_t)B_ * S_ * D_;     // 4,194,304 elements
  const size_t NW   = (size_t)D_ * D_;          // 1,048,576
  unsigned short* qh  = (unsigned short*)d_ws;  // bf16 [B,S,D]
  unsigned short* kh  = qh + NTOK;
  unsigned short* vt  = kh + NTOK;              // bf16 [B*H, 64, S]
  unsigned short* xb  = vt + NTOK;              // bf16 [B,S,D]; reused as ab
  unsigned short* wqb = xb + NTOK;
  unsigned short* wkb = wqb + NW;
  unsigned short* wvb = wkb + NW;
  unsigned short* wob = wvb + NW;
  unsigned short* ab  = xb;                     // alias: xb dead after QKV gemm

  // fp32 -> bf16 casts
  cast5_bf16<<<dim3(4096), 256, 0, stream>>>(
      x, Wq, Wk, Wv, Wo, xb, wqb, wkb, wvb, wob);

  // fused QKV projection + RoPE + Q-scale + direct-V^T (operand swap), BK=64
  gemm_qkv<<<dim3(D_ / 128, (B_ * S_) / 128, 3), 256, 0, stream>>>(
      xb, wqb, wkb, wvb, qh, kh, vt, tp);

  // paired causal MFMA flash attention (fixed-max softmax) -> bf16 ab
  attn_mfma<<<dim3(16, B_ * H_), 256, 0, stream>>>(qh, kh, vt, ab);

  // output projection, 64x128 tiles, BK=64 (512 blocks = 2/CU) -> fp32 out
  gemm_wo<<<dim3(D_ / 128, (B_ * S_) / 64), 256, 0, stream>>>(ab, wob, out);
}